// Round 1
// baseline (13554.854 us; speedup 1.0000x reference)
//
#include <hip/hip_runtime.h>

// HierarchicalCSNet — fp32 direct-conv baseline.
// Shapes: x (1,1,256,256); G=8 groups, BS=32.
// Per group m:
//   s  = conv(x, sample_w[m], k=32, s=32)            -> (13, 8, 8)
//   r  = reshape_adap(1x1conv(s, up_w[m]) + up_b)    -> (1, 256, 256)   [fused kernel]
//   h  = PReLU(conv3x3(r, h1_w[m]) + h1_b, h1_a)     -> (64, 256, 256)
//   feature = (m==0) ? h : PReLU(conv3x3(cat(feature,h), fus_w[m-1]) + fus_b, fus_a)
//   t  = PReLU(conv3x3 t2) ; t = PReLU(conv3x3 t3) ; t = PReLU(conv3x3 t4)
//   out[m] = conv3x3(t, t5_w[m]) + t5_b
constexpr int H = 256, W = 256, NPIX = H * W;

// ---------------------------------------------------------------- sampling
// One wave per output element (c,i,j): 13*64 = 832 outputs, 1024-MAC reduce.
__global__ __launch_bounds__(256)
void sample_k(const float* __restrict__ x, const float* __restrict__ sw,
              float* __restrict__ s)
{
    int wid  = blockIdx.x * 4 + (threadIdx.x >> 6);
    int lane = threadIdx.x & 63;
    if (wid >= 13 * 64) return;
    int c = wid >> 6;
    int ij = wid & 63;
    int i = ij >> 3, j = ij & 7;
    float acc = 0.f;
    for (int k = lane; k < 1024; k += 64) {
        int p = k >> 5, q = k & 31;
        acc += x[(i * 32 + p) * W + (j * 32 + q)] * sw[c * 1024 + k];
    }
    #pragma unroll
    for (int off = 32; off > 0; off >>= 1) acc += __shfl_down(acc, off, 64);
    if (lane == 0) s[wid] = acc;
}

// ------------------------------------------------- up(1x1) + reshape_adap
// r[y][x] = sum_c up_w[oc][c] * s[c][y/32][x/32] + up_b[oc], oc=(y%32)*32+(x%32)
__global__ __launch_bounds__(256)
void upreshape_k(const float* __restrict__ s, const float* __restrict__ uw,
                 const float* __restrict__ ub, float* __restrict__ r)
{
    int xx = threadIdx.x, yy = blockIdx.x;
    int i = yy >> 5, p = yy & 31, j = xx >> 5, q = xx & 31;
    int oc = p * 32 + q;
    float acc = ub[oc];
    #pragma unroll
    for (int c = 0; c < 13; ++c)
        acc = fmaf(uw[oc * 13 + c], s[c * 64 + i * 8 + j], acc);
    r[yy * W + xx] = acc;
}

// ---------------------------------------------------------------- conv3x3
// Block = one image row (256 threads); each thread: 1 pixel, COUT accumulators.
// Two input tensors (for the concat case) — in1 channels follow in0's in the
// weight layout. Weights are wave-uniform -> scalar loads.
template <int CIN0, int CIN1, int COUT, bool PRELU>
__global__ __launch_bounds__(256)
void conv3x3_k(const float* __restrict__ in0, const float* __restrict__ in1,
               const float* __restrict__ w, const float* __restrict__ b,
               const float* __restrict__ a, float* __restrict__ out)
{
    const int x = threadIdx.x;
    const int y = blockIdx.x;
    constexpr int CINT = CIN0 + CIN1;

    float acc[COUT];
    #pragma unroll
    for (int co = 0; co < COUT; ++co) acc[co] = b[co];

    const bool ym = (y > 0), yp = (y < H - 1);
    const bool xm = (x > 0), xp = (x < W - 1);

    auto do_cin = [&](const float* __restrict__ ip, int ciw) {
        float v[9];
        #pragma unroll
        for (int dy = -1; dy <= 1; ++dy) {
            const bool yok = (dy < 0) ? ym : ((dy > 0) ? yp : true);
            const float* row = ip + (y + dy) * W;
            v[(dy + 1) * 3 + 0] = (yok && xm) ? row[x - 1] : 0.f;
            v[(dy + 1) * 3 + 1] = yok ? row[x] : 0.f;
            v[(dy + 1) * 3 + 2] = (yok && xp) ? row[x + 1] : 0.f;
        }
        #pragma unroll
        for (int co = 0; co < COUT; ++co) {
            const float* wc = w + (co * CINT + ciw) * 9;
            #pragma unroll
            for (int k = 0; k < 9; ++k) acc[co] = fmaf(v[k], wc[k], acc[co]);
        }
    };

    for (int ci = 0; ci < CIN0; ++ci) do_cin(in0 + ci * NPIX, ci);
    if (CIN1 > 0)
        for (int ci = 0; ci < CIN1; ++ci) do_cin(in1 + ci * NPIX, CIN0 + ci);

    const float slope = PRELU ? a[0] : 0.f;
    #pragma unroll
    for (int co = 0; co < COUT; ++co) {
        float v = acc[co];
        if (PRELU) v = (v >= 0.f) ? v : slope * v;
        out[co * NPIX + y * W + x] = v;
    }
}

extern "C" void kernel_launch(void* const* d_in, const int* in_sizes, int n_in,
                              void* d_out, int out_size, void* d_ws, size_t ws_size,
                              hipStream_t stream)
{
    const float* x        = (const float*)d_in[0];
    const float* sample_w = (const float*)d_in[1];   // (8,13,1,32,32)
    const float* up_w     = (const float*)d_in[2];   // (8,1024,13,1,1)
    const float* up_b     = (const float*)d_in[3];   // (8,1024)
    const float* h1_w     = (const float*)d_in[4];   // (8,64,1,3,3)
    const float* h1_b     = (const float*)d_in[5];   // (8,64)
    const float* h1_a     = (const float*)d_in[6];   // (8,)
    const float* fus_w    = (const float*)d_in[7];   // (7,64,128,3,3)
    const float* fus_b    = (const float*)d_in[8];   // (7,64)
    const float* fus_a    = (const float*)d_in[9];   // (7,)
    const float* t2_w     = (const float*)d_in[10];  // (8,64,64,3,3)
    const float* t2_b     = (const float*)d_in[11];
    const float* t2_a     = (const float*)d_in[12];
    const float* t3_w     = (const float*)d_in[13];
    const float* t3_b     = (const float*)d_in[14];
    const float* t3_a     = (const float*)d_in[15];
    const float* t4_w     = (const float*)d_in[16];
    const float* t4_b     = (const float*)d_in[17];
    const float* t4_a     = (const float*)d_in[18];
    const float* t5_w     = (const float*)d_in[19];  // (8,1,64,3,3)
    const float* t5_b     = (const float*)d_in[20];  // (8,1)

    float* out = (float*)d_out;
    float* ws  = (float*)d_ws;

    float* s_buf = ws;                    // 13*64
    float* r_buf = s_buf + 1024;          // 65536
    float* fA    = r_buf + NPIX;          // 64 planes each below
    float* fB    = fA + 64 * NPIX;
    float* hb    = fB + 64 * NPIX;
    float* t1    = hb + 64 * NPIX;
    float* t2b   = t1 + 64 * NPIX;

    float* feat = fA;
    float* feat_alt = fB;

    for (int m = 0; m < 8; ++m) {
        sample_k<<<208, 256, 0, stream>>>(x, sample_w + m * 13 * 1024, s_buf);
        upreshape_k<<<256, 256, 0, stream>>>(s_buf, up_w + m * 1024 * 13,
                                             up_b + m * 1024, r_buf);
        if (m == 0) {
            conv3x3_k<1, 0, 64, true><<<256, 256, 0, stream>>>(
                r_buf, nullptr, h1_w + m * 64 * 9, h1_b + m * 64, h1_a + m, feat);
        } else {
            conv3x3_k<1, 0, 64, true><<<256, 256, 0, stream>>>(
                r_buf, nullptr, h1_w + m * 64 * 9, h1_b + m * 64, h1_a + m, hb);
            conv3x3_k<64, 64, 64, true><<<256, 256, 0, stream>>>(
                feat, hb, fus_w + (size_t)(m - 1) * 64 * 128 * 9,
                fus_b + (m - 1) * 64, fus_a + (m - 1), feat_alt);
            float* tmp = feat; feat = feat_alt; feat_alt = tmp;
        }
        conv3x3_k<64, 0, 64, true><<<256, 256, 0, stream>>>(
            feat, nullptr, t2_w + (size_t)m * 64 * 64 * 9, t2_b + m * 64, t2_a + m, t1);
        conv3x3_k<64, 0, 64, true><<<256, 256, 0, stream>>>(
            t1, nullptr, t3_w + (size_t)m * 64 * 64 * 9, t3_b + m * 64, t3_a + m, t2b);
        conv3x3_k<64, 0, 64, true><<<256, 256, 0, stream>>>(
            t2b, nullptr, t4_w + (size_t)m * 64 * 64 * 9, t4_b + m * 64, t4_a + m, t1);
        conv3x3_k<64, 0, 1, false><<<256, 256, 0, stream>>>(
            t1, nullptr, t5_w + (size_t)m * 64 * 9, t5_b + m, nullptr, out + m * NPIX);
    }
}

// Round 2
// 1061.148 us; speedup vs baseline: 12.7738x; 12.7738x over previous
//
#include <hip/hip_runtime.h>

// HierarchicalCSNet — f16 MFMA implicit-GEMM conv version.
// Features stored NHWC f16: f[y][x][c], 64 channels = 128B per pixel.
// conv3x3 (64->64 and 128->64 via 2 passes) uses mfma_f32_32x32x16_f16:
//   block = 4 waves, tile = 64co x 128px (one x-half of a row), grid = 512.
//   LDS: weights [9][64][64] f16 (pre-swizzled) + input [3][130][64] f16.
//   XOR swizzle on the 16B ci-chunk index with (pixel&7)/(co&7) kills the
//   128B-stride 32-way bank conflict.
constexpr int H = 256, W = 256, NPIX = H * W;

typedef _Float16 half8 __attribute__((ext_vector_type(8)));
typedef _Float16 half4 __attribute__((ext_vector_type(4)));
typedef float    f32x4 __attribute__((ext_vector_type(4)));
typedef float    f32x16 __attribute__((ext_vector_type(16)));

// ---------------------------------------------------------------- sampling
__global__ __launch_bounds__(256)
void sample_k(const float* __restrict__ x, const float* __restrict__ sw,
              float* __restrict__ s)
{
    int wid  = blockIdx.x * 4 + (threadIdx.x >> 6);
    int lane = threadIdx.x & 63;
    if (wid >= 13 * 64) return;
    int c = wid >> 6;
    int ij = wid & 63;
    int i = ij >> 3, j = ij & 7;
    float acc = 0.f;
    for (int k = lane; k < 1024; k += 64) {
        int p = k >> 5, q = k & 31;
        acc += x[(i * 32 + p) * W + (j * 32 + q)] * sw[c * 1024 + k];
    }
    #pragma unroll
    for (int off = 32; off > 0; off >>= 1) acc += __shfl_down(acc, off, 64);
    if (lane == 0) s[wid] = acc;
}

// ------------------------------------------------- up(1x1) + reshape_adap
__global__ __launch_bounds__(256)
void upreshape_k(const float* __restrict__ s, const float* __restrict__ uw,
                 const float* __restrict__ ub, float* __restrict__ r)
{
    int xx = threadIdx.x, yy = blockIdx.x;
    int i = yy >> 5, p = yy & 31, j = xx >> 5, q = xx & 31;
    int oc = p * 32 + q;
    float acc = ub[oc];
    #pragma unroll
    for (int c = 0; c < 13; ++c)
        acc = fmaf(uw[oc * 13 + c], s[c * 64 + i * 8 + j], acc);
    r[yy * W + xx] = acc;
}

// --------------------------------------------- h1: conv 1->64, out NHWC f16
__global__ __launch_bounds__(256)
void h1_k(const float* __restrict__ r, const float* __restrict__ w,
          const float* __restrict__ b, const float* __restrict__ a,
          _Float16* __restrict__ out)
{
    const int x = threadIdx.x, y = blockIdx.x;
    float v[9];
    #pragma unroll
    for (int dy = 0; dy < 3; ++dy) {
        int gy = y + dy - 1;
        #pragma unroll
        for (int dx = 0; dx < 3; ++dx) {
            int gx = x + dx - 1;
            v[dy*3+dx] = ((unsigned)gy < 256u && (unsigned)gx < 256u)
                       ? r[(gy << 8) + gx] : 0.f;
        }
    }
    const float slope = a[0];
    _Float16* op = out + (((y << 8) + x) << 6);
    #pragma unroll
    for (int cg = 0; cg < 8; ++cg) {
        half8 o;
        #pragma unroll
        for (int j = 0; j < 8; ++j) {
            int co = cg * 8 + j;
            float acc = b[co];
            #pragma unroll
            for (int k = 0; k < 9; ++k) acc = fmaf(v[k], w[co*9+k], acc);
            acc = acc >= 0.f ? acc : slope * acc;
            o[j] = (_Float16)acc;
        }
        *(half8*)(op + cg * 8) = o;
    }
}

// -------------------------------------- weight prep: fp32 [co][ci][9] ->
// f16 blocks [tap][co][chunk c][8], chunk pre-swizzled: position c holds
// data of ci-chunk (c ^ (co&7)), so a LINEAR copy into LDS lands swizzled.
// blocks 0-7: t2 (m), 8-15: t3, 16-23: t4, 24+2f+half: fusion conv f.
__global__ __launch_bounds__(256)
void wprep_k(const float* __restrict__ t2w, const float* __restrict__ t3w,
             const float* __restrict__ t4w, const float* __restrict__ fusw,
             _Float16* __restrict__ w16)
{
    int tid = blockIdx.x * 256 + threadIdx.x;
    if (tid >= 38 * 36864) return;
    int blk = tid / 36864, r2 = tid % 36864;
    int e = r2 & 7, c = (r2 >> 3) & 7, co = (r2 >> 6) & 63, tap = r2 >> 12;
    const float* src; int cin, cib;
    if (blk < 24) {
        int which = blk >> 3, m = blk & 7;
        src = (which == 0 ? t2w : which == 1 ? t3w : t4w) + (size_t)m * 64 * 64 * 9;
        cin = 64; cib = 0;
    } else {
        int f = (blk - 24) >> 1; cib = ((blk - 24) & 1) * 64;
        src = fusw + (size_t)f * 64 * 128 * 9; cin = 128;
    }
    int ci = cib + ((c ^ (co & 7)) << 3) + e;
    w16[tid] = (_Float16)src[((size_t)co * cin + ci) * 9 + tap];
}

// ------------------------------------------------ MFMA conv3x3 (64ci/pass)
// grid 512: y = bid>>1, x-half = bid&1. 4 waves; wave w: co 0..63 x 32 px.
template <int PASSES>
__global__ __launch_bounds__(256)
void conv_mfma_k(const _Float16* __restrict__ in0, const _Float16* __restrict__ in1,
                 const _Float16* __restrict__ w0, const _Float16* __restrict__ w1,
                 const float* __restrict__ bias, const float* __restrict__ alpha,
                 _Float16* __restrict__ out)
{
    const int lane = threadIdx.x & 63;
    const int wv   = threadIdx.x >> 6;
    const int y    = blockIdx.x >> 1;
    const int x0   = (blockIdx.x & 1) * 128;
    const int p0   = wv * 32;
    const int h    = lane >> 5;
    const int cl   = lane & 31;

    extern __shared__ __align__(16) char smem[];
    _Float16* lw = (_Float16*)smem;             // [9][64][8][8]  73728 B
    _Float16* li = (_Float16*)(smem + 73728);   // [3][130][8][8] 49920 B

    f32x16 acc0, acc1;
    #pragma unroll
    for (int q = 0; q < 4; ++q)
        #pragma unroll
        for (int j = 0; j < 4; ++j) {
            int co = q * 8 + 4 * h + j;
            acc0[q*4+j] = bias[co];
            acc1[q*4+j] = bias[co + 32];
        }

    #pragma unroll
    for (int pass = 0; pass < PASSES; ++pass) {
        const _Float16* in   = pass ? in1 : in0;
        const _Float16* wsrc = pass ? w1 : w0;
        if (pass) __syncthreads();              // LDS reuse fence
        // stage weights (linear, pre-swizzled): 4608 16B chunks
        #pragma unroll 2
        for (int i = 0; i < 18; ++i) {
            int ch = i * 256 + threadIdx.x;
            *(f32x4*)(lw + ch * 8) = *(const f32x4*)(wsrc + ch * 8);
        }
        // stage input halo [3][130][64] with zero-pad + XOR swizzle
        for (int i = 0; i < 13; ++i) {
            int f = i * 256 + threadIdx.x;
            if (f < 3120) {
                int c = f & 7, px = (f >> 3) % 130, r = f / 1040;
                int gy = y + r - 1, gx = x0 - 1 + px;
                f32x4 v = {0.f, 0.f, 0.f, 0.f};
                if ((unsigned)gy < 256u && (unsigned)gx < 256u)
                    v = *(const f32x4*)(in + ((((gy << 8) + gx) << 6) + c * 8));
                *(f32x4*)(li + (((r * 130 + px) << 3) + (c ^ (px & 7))) * 8) = v;
            }
        }
        __syncthreads();
        // compute: 9 taps x 4 K-chunks, 2 co-tiles
        #pragma unroll
        for (int tap = 0; tap < 9; ++tap) {
            const int dy = tap / 3, dx = tap % 3 - 1;
            const int px = p0 + cl + dx + 1;
            #pragma unroll
            for (int kk = 0; kk < 4; ++kk) {
                int c = kk * 2 + h;
                half8 a0 = *(const half8*)(lw + (((tap*64 + cl     ) << 3) + (c ^ (cl & 7))) * 8);
                half8 a1 = *(const half8*)(lw + (((tap*64 + cl + 32) << 3) + (c ^ (cl & 7))) * 8);
                half8 bf = *(const half8*)(li + (((dy*130 + px     ) << 3) + (c ^ (px & 7))) * 8);
                acc0 = __builtin_amdgcn_mfma_f32_32x32x16_f16(a0, bf, acc0, 0, 0, 0);
                acc1 = __builtin_amdgcn_mfma_f32_32x32x16_f16(a1, bf, acc1, 0, 0, 0);
            }
        }
    }
    // store: D col=lane&31=px, row=(r&3)+8*(r>>2)+4*h=co
    const float slope = alpha[0];
    const int pix = (y << 8) + x0 + p0 + cl;
    #pragma unroll
    for (int q = 0; q < 4; ++q) {
        half4 v0, v1;
        #pragma unroll
        for (int j = 0; j < 4; ++j) {
            float xv = acc0[q*4+j]; xv = xv >= 0.f ? xv : slope * xv; v0[j] = (_Float16)xv;
            float yv = acc1[q*4+j]; yv = yv >= 0.f ? yv : slope * yv; v1[j] = (_Float16)yv;
        }
        int co0 = q * 8 + 4 * h;
        *(half4*)(out + (pix << 6) + co0)      = v0;
        *(half4*)(out + (pix << 6) + co0 + 32) = v1;
    }
}

// ------------------------------------------------------- t5: conv 64->1
__global__ __launch_bounds__(256)
void t5_k(const _Float16* __restrict__ in, const float* __restrict__ w,
          const float* __restrict__ b, float* __restrict__ out)
{
    const int x = threadIdx.x, y = blockIdx.x;
    float acc = b[0];
    #pragma unroll
    for (int dy = 0; dy < 3; ++dy) {
        int gy = y + dy - 1; if ((unsigned)gy >= 256u) continue;
        #pragma unroll
        for (int dx = 0; dx < 3; ++dx) {
            int gx = x + dx - 1; if ((unsigned)gx >= 256u) continue;
            const _Float16* p = in + (((gy << 8) + gx) << 6);
            int tap = dy * 3 + dx;
            #pragma unroll
            for (int cg = 0; cg < 8; ++cg) {
                half8 vv = *(const half8*)(p + cg * 8);
                #pragma unroll
                for (int e = 0; e < 8; ++e)
                    acc = fmaf((float)vv[e], w[(cg*8+e)*9 + tap], acc);
            }
        }
    }
    out[(y << 8) + x] = acc;
}

extern "C" void kernel_launch(void* const* d_in, const int* in_sizes, int n_in,
                              void* d_out, int out_size, void* d_ws, size_t ws_size,
                              hipStream_t stream)
{
    const float* x        = (const float*)d_in[0];
    const float* sample_w = (const float*)d_in[1];
    const float* up_w     = (const float*)d_in[2];
    const float* up_b     = (const float*)d_in[3];
    const float* h1_w     = (const float*)d_in[4];
    const float* h1_b     = (const float*)d_in[5];
    const float* h1_a     = (const float*)d_in[6];
    const float* fus_w    = (const float*)d_in[7];
    const float* fus_b    = (const float*)d_in[8];
    const float* fus_a    = (const float*)d_in[9];
    const float* t2_w     = (const float*)d_in[10];
    const float* t2_b     = (const float*)d_in[11];
    const float* t2_a     = (const float*)d_in[12];
    const float* t3_w     = (const float*)d_in[13];
    const float* t3_b     = (const float*)d_in[14];
    const float* t3_a     = (const float*)d_in[15];
    const float* t4_w     = (const float*)d_in[16];
    const float* t4_b     = (const float*)d_in[17];
    const float* t4_a     = (const float*)d_in[18];
    const float* t5_w     = (const float*)d_in[19];
    const float* t5_b     = (const float*)d_in[20];

    float* out = (float*)d_out;
    char*  wsb = (char*)d_ws;

    float*    s_buf = (float*)wsb;                         // 4 KB
    float*    r_buf = (float*)(wsb + 4096);                // 256 KB
    const size_t PL = (size_t)64 * NPIX * 2;               // 8 MB per plane
    _Float16* fA  = (_Float16*)(wsb + 266240);
    _Float16* fB  = (_Float16*)(wsb + 266240 + PL);
    _Float16* hb  = (_Float16*)(wsb + 266240 + 2*PL);
    _Float16* t1  = (_Float16*)(wsb + 266240 + 3*PL);
    _Float16* t2b = (_Float16*)(wsb + 266240 + 4*PL);
    _Float16* w16 = (_Float16*)(wsb + 266240 + 5*PL);      // 38 * 36864 f16

    auto wblk = [&](int b) { return w16 + (size_t)b * 36864; };

    wprep_k<<<5472, 256, 0, stream>>>(t2_w, t3_w, t4_w, fus_w, w16);

    const size_t LDSB = 73728 + 49920;
    _Float16* feat = fA;
    _Float16* feat_alt = fB;

    for (int m = 0; m < 8; ++m) {
        sample_k<<<208, 256, 0, stream>>>(x, sample_w + m * 13 * 1024, s_buf);
        upreshape_k<<<256, 256, 0, stream>>>(s_buf, up_w + m * 1024 * 13,
                                             up_b + m * 1024, r_buf);
        if (m == 0) {
            h1_k<<<256, 256, 0, stream>>>(r_buf, h1_w + m * 64 * 9,
                                          h1_b + m * 64, h1_a + m, feat);
        } else {
            h1_k<<<256, 256, 0, stream>>>(r_buf, h1_w + m * 64 * 9,
                                          h1_b + m * 64, h1_a + m, hb);
            conv_mfma_k<2><<<512, 256, LDSB, stream>>>(
                feat, hb, wblk(24 + (m - 1) * 2), wblk(24 + (m - 1) * 2 + 1),
                fus_b + (m - 1) * 64, fus_a + (m - 1), feat_alt);
            _Float16* tmp = feat; feat = feat_alt; feat_alt = tmp;
        }
        conv_mfma_k<1><<<512, 256, LDSB, stream>>>(
            feat, nullptr, wblk(m), nullptr, t2_b + m * 64, t2_a + m, t1);
        conv_mfma_k<1><<<512, 256, LDSB, stream>>>(
            t1, nullptr, wblk(8 + m), nullptr, t3_b + m * 64, t3_a + m, t2b);
        conv_mfma_k<1><<<512, 256, LDSB, stream>>>(
            t2b, nullptr, wblk(16 + m), nullptr, t4_b + m * 64, t4_a + m, t1);
        t5_k<<<256, 256, 0, stream>>>(t1, t5_w + (size_t)m * 64 * 9,
                                      t5_b + m, out + m * NPIX);
    }
}

// Round 3
// 999.293 us; speedup vs baseline: 13.5644x; 1.0619x over previous
//
#include <hip/hip_runtime.h>

// HierarchicalCSNet — f16 MFMA implicit-GEMM, A-from-global, padded planes.
// Feature planes: padded NHWC f16 [258][258][64], borders zero (= conv pad).
// conv3x3: block = 4 waves, tile 64co x 128px (half row), grid 512.
//   LDS: input halo only [3][130][8ch][8] f16 = 49.9KB -> 2 blocks/CU.
//   Staging via global_load_lds (linear dest, pre-swizzled global source).
//   A (weights) loaded per-wave from global layout [tap][kk][h][co][8] (L2-hot).
constexpr int H = 256, W = 256, NPIX = H * W;
constexpr int PW = 258;
constexpr size_t PLANE = (size_t)PW * PW * 64;      // f16 elements

typedef _Float16 half8 __attribute__((ext_vector_type(8)));
typedef _Float16 half4 __attribute__((ext_vector_type(4)));
typedef float    f32x4 __attribute__((ext_vector_type(4)));
typedef float    f32x16 __attribute__((ext_vector_type(16)));

__device__ __forceinline__ void gl16(const _Float16* g, _Float16* l)
{
    __builtin_amdgcn_global_load_lds(
        (const __attribute__((address_space(1))) unsigned int*)g,
        (__attribute__((address_space(3))) unsigned int*)l, 16, 0, 0);
}

// ---------------------------------------------------- border zero (5 planes)
__global__ __launch_bounds__(256)
void border_k(_Float16* __restrict__ planes)
{
    int tid = blockIdx.x * 256 + threadIdx.x;
    if (tid >= 5 * 1028 * 8) return;
    int c = tid & 7, rem = tid >> 3;
    int p = rem / 1028, b = rem % 1028;
    int gy, gx;
    if (b < 258)      { gy = 0;           gx = b; }
    else if (b < 516) { gy = 257;         gx = b - 258; }
    else if (b < 772) { gy = b - 516 + 1; gx = 0; }
    else              { gy = b - 772 + 1; gx = 257; }
    f32x4 z = {0.f, 0.f, 0.f, 0.f};
    *(f32x4*)(planes + (size_t)p * PLANE + ((size_t)(gy * PW + gx) * 64) + c * 8) = z;
}

// --------------------------- fused sampling + up(1x1) + reshape_adap (all m)
__global__ __launch_bounds__(256)
void sampup_k(const float* __restrict__ x, const float* __restrict__ sw,
              const float* __restrict__ uw, const float* __restrict__ ub,
              float* __restrict__ r_all)
{
    int m = blockIdx.x >> 6, ij = blockIdx.x & 63;
    int i = ij >> 3, j = ij & 7;
    __shared__ float s_lds[16];
    int t = threadIdx.x;
    if (t < 208) {
        int c = t >> 4, sub = t & 15;
        float acc = 0.f;
        for (int k = sub * 64; k < sub * 64 + 64; ++k) {
            int p = k >> 5, q = k & 31;
            acc += x[(i * 32 + p) * W + (j * 32 + q)] * sw[(m * 13 + c) * 1024 + k];
        }
        #pragma unroll
        for (int off = 8; off; off >>= 1) acc += __shfl_down(acc, off, 16);
        if (sub == 0) s_lds[c] = acc;
    }
    __syncthreads();
    const float* uwm = uw + m * 1024 * 13;
    float* rm = r_all + m * NPIX;
    #pragma unroll
    for (int pi = 0; pi < 4; ++pi) {
        int px = pi * 256 + t;
        int p = px >> 5, q = px & 31;
        int oc = p * 32 + q;
        float acc = ub[m * 1024 + oc];
        #pragma unroll
        for (int c = 0; c < 13; ++c) acc = fmaf(uwm[oc * 13 + c], s_lds[c], acc);
        rm[((i * 32 + p) << 8) + j * 32 + q] = acc;
    }
}

// --------------------------------------- h1: conv 1->64, writes padded plane
__global__ __launch_bounds__(256)
void h1_k(const float* __restrict__ r, const float* __restrict__ w,
          const float* __restrict__ b, const float* __restrict__ a,
          _Float16* __restrict__ out)
{
    const int x = threadIdx.x, y = blockIdx.x;
    float v[9];
    #pragma unroll
    for (int dy = 0; dy < 3; ++dy) {
        int gy = y + dy - 1;
        #pragma unroll
        for (int dx = 0; dx < 3; ++dx) {
            int gx = x + dx - 1;
            v[dy*3+dx] = ((unsigned)gy < 256u && (unsigned)gx < 256u)
                       ? r[(gy << 8) + gx] : 0.f;
        }
    }
    const float slope = a[0];
    _Float16* op = out + ((size_t)((y + 1) * PW + (x + 1))) * 64;
    #pragma unroll
    for (int cg = 0; cg < 8; ++cg) {
        half8 o;
        #pragma unroll
        for (int j = 0; j < 8; ++j) {
            int co = cg * 8 + j;
            float acc = b[co];
            #pragma unroll
            for (int k = 0; k < 9; ++k) acc = fmaf(v[k], w[co*9+k], acc);
            acc = acc >= 0.f ? acc : slope * acc;
            o[j] = (_Float16)acc;
        }
        *(half8*)(op + cg * 8) = o;
    }
}

// ------- weight prep: fp32 [co][ci][9] -> f16 [blk][tap][kk][h][co][8]
// ci = (kk*2+h)*8+e. blocks 0-7: t2, 8-15: t3, 16-23: t4, 24+2f+half: fusion.
__global__ __launch_bounds__(256)
void wprep_k(const float* __restrict__ t2w, const float* __restrict__ t3w,
             const float* __restrict__ t4w, const float* __restrict__ fusw,
             _Float16* __restrict__ w16)
{
    int tid = blockIdx.x * 256 + threadIdx.x;
    if (tid >= 38 * 36864) return;
    int blk = tid / 36864, r2 = tid % 36864;
    int e = r2 & 7, co = (r2 >> 3) & 63, hh = (r2 >> 9) & 1, kk = (r2 >> 10) & 3,
        tap = r2 >> 12;
    const float* src; int cin, cib;
    if (blk < 24) {
        int which = blk >> 3, m = blk & 7;
        src = (which == 0 ? t2w : which == 1 ? t3w : t4w) + (size_t)m * 64 * 64 * 9;
        cin = 64; cib = 0;
    } else {
        int f = (blk - 24) >> 1; cib = ((blk - 24) & 1) * 64;
        src = fusw + (size_t)f * 64 * 128 * 9; cin = 128;
    }
    int ci = cib + (kk * 2 + hh) * 8 + e;
    w16[tid] = (_Float16)src[((size_t)co * cin + ci) * 9 + tap];
}

// ---------------------------------------------- MFMA conv3x3 (64 ci / pass)
template <int PASSES>
__global__ __launch_bounds__(256, 2)
void conv_mfma_k(const _Float16* __restrict__ in0, const _Float16* __restrict__ in1,
                 const _Float16* __restrict__ w0, const _Float16* __restrict__ w1,
                 const float* __restrict__ bias, const float* __restrict__ alpha,
                 _Float16* __restrict__ out)
{
    const int lane = threadIdx.x & 63;
    const int wv   = threadIdx.x >> 6;
    const int y    = blockIdx.x >> 1;
    const int x0   = (blockIdx.x & 1) * 128;
    const int p0   = wv * 32;
    const int h    = lane >> 5;
    const int cl   = lane & 31;

    extern __shared__ __align__(16) char smem[];
    _Float16* li = (_Float16*)smem;           // [3][130][8][8] = 49920 B

    f32x16 acc0, acc1;
    #pragma unroll
    for (int q = 0; q < 4; ++q)
        #pragma unroll
        for (int j = 0; j < 4; ++j) {
            int co = q * 8 + 4 * h + j;
            acc0[q*4+j] = bias[co];
            acc1[q*4+j] = bias[co + 32];
        }

    #pragma unroll
    for (int pass = 0; pass < PASSES; ++pass) {
        const _Float16* in   = pass ? in1 : in0;
        const _Float16* wsrc = pass ? w1 : w0;
        if (pass) __syncthreads();            // LDS reuse fence
        // stage [3][130][8] chunks = 3120; wave wv: chunks [wv*780, wv*780+780)
        {
            const int base = wv * 780;
            #pragma unroll
            for (int i = 0; i < 13; ++i) {
                int Lc = base + i * 64 + lane;
                int r = Lc / 1040, rem = Lc % 1040;
                int px = rem >> 3, c = rem & 7;
                const _Float16* src = in +
                    ((size_t)((y + r) * PW + (x0 + px)) * 64 + (c ^ (px & 7)) * 8);
                _Float16* dst = li + (size_t)(base + i * 64) * 8;
                if (i < 12 || lane < 12) gl16(src, dst);
            }
        }
        __syncthreads();                      // drains vmcnt before reads
        // compute: 9 taps x 4 K-chunks x 2 co-tiles; A from global (L2-hot)
        #pragma unroll
        for (int tap = 0; tap < 9; ++tap) {
            const int dy = tap / 3;
            const int pxl = p0 + cl + tap % 3;
            #pragma unroll
            for (int kk = 0; kk < 4; ++kk) {
                const int c = kk * 2 + h;
                half8 a0 = *(const half8*)(wsrc + ((size_t)(((tap*4+kk)*2+h)*64 + cl) * 8));
                half8 a1 = *(const half8*)(wsrc + ((size_t)(((tap*4+kk)*2+h)*64 + 32 + cl) * 8));
                half8 bf = *(const half8*)(li + ((size_t)((dy*130 + pxl)*8 + (c ^ (pxl & 7))) * 8));
                acc0 = __builtin_amdgcn_mfma_f32_32x32x16_f16(a0, bf, acc0, 0, 0, 0);
                acc1 = __builtin_amdgcn_mfma_f32_32x32x16_f16(a1, bf, acc1, 0, 0, 0);
            }
        }
    }
    // store: D col=lane&31=px, row=(r&3)+8*(r>>2)+4*h=co ; padded interior
    const float slope = alpha[0];
    const size_t gp = (size_t)((y + 1) * PW + (x0 + p0 + cl + 1)) * 64;
    #pragma unroll
    for (int q = 0; q < 4; ++q) {
        half4 v0, v1;
        #pragma unroll
        for (int j = 0; j < 4; ++j) {
            float xv = acc0[q*4+j]; xv = xv >= 0.f ? xv : slope * xv; v0[j] = (_Float16)xv;
            float yv = acc1[q*4+j]; yv = yv >= 0.f ? yv : slope * yv; v1[j] = (_Float16)yv;
        }
        int co0 = q * 8 + 4 * h;
        *(half4*)(out + gp + co0)      = v0;
        *(half4*)(out + gp + co0 + 32) = v1;
    }
}

// ------------------------------------------ t5: conv 64->1 (padded input)
__global__ __launch_bounds__(256)
void t5_k(const _Float16* __restrict__ in, const float* __restrict__ w,
          const float* __restrict__ b, float* __restrict__ out)
{
    const int x = threadIdx.x, y = blockIdx.x;
    float acc = b[0];
    #pragma unroll
    for (int dy = 0; dy < 3; ++dy) {
        #pragma unroll
        for (int dx = 0; dx < 3; ++dx) {
            const _Float16* p = in + (size_t)((y + dy) * PW + (x + dx)) * 64;
            int tap = dy * 3 + dx;
            #pragma unroll
            for (int cg = 0; cg < 8; ++cg) {
                half8 vv = *(const half8*)(p + cg * 8);
                #pragma unroll
                for (int e = 0; e < 8; ++e)
                    acc = fmaf((float)vv[e], w[(cg*8+e)*9 + tap], acc);
            }
        }
    }
    out[(y << 8) + x] = acc;
}

extern "C" void kernel_launch(void* const* d_in, const int* in_sizes, int n_in,
                              void* d_out, int out_size, void* d_ws, size_t ws_size,
                              hipStream_t stream)
{
    const float* x        = (const float*)d_in[0];
    const float* sample_w = (const float*)d_in[1];
    const float* up_w     = (const float*)d_in[2];
    const float* up_b     = (const float*)d_in[3];
    const float* h1_w     = (const float*)d_in[4];
    const float* h1_b     = (const float*)d_in[5];
    const float* h1_a     = (const float*)d_in[6];
    const float* fus_w    = (const float*)d_in[7];
    const float* fus_b    = (const float*)d_in[8];
    const float* fus_a    = (const float*)d_in[9];
    const float* t2_w     = (const float*)d_in[10];
    const float* t2_b     = (const float*)d_in[11];
    const float* t2_a     = (const float*)d_in[12];
    const float* t3_w     = (const float*)d_in[13];
    const float* t3_b     = (const float*)d_in[14];
    const float* t3_a     = (const float*)d_in[15];
    const float* t4_w     = (const float*)d_in[16];
    const float* t4_b     = (const float*)d_in[17];
    const float* t4_a     = (const float*)d_in[18];
    const float* t5_w     = (const float*)d_in[19];
    const float* t5_b     = (const float*)d_in[20];

    float* out = (float*)d_out;
    char*  wsb = (char*)d_ws;

    _Float16* w16    = (_Float16*)wsb;                        // 2,801,664 B
    float*    r_all  = (float*)(wsb + 2801664);               // 2,097,152 B
    _Float16* planes = (_Float16*)(wsb + 4898816);            // 5 x 8,520,192 B

    _Float16* fA  = planes;
    _Float16* fB  = planes + PLANE;
    _Float16* hb  = planes + 2 * PLANE;
    _Float16* t1  = planes + 3 * PLANE;
    _Float16* t2b = planes + 4 * PLANE;

    auto wblk = [&](int b) { return w16 + (size_t)b * 36864; };

    border_k<<<161, 256, 0, stream>>>(planes);
    wprep_k<<<5472, 256, 0, stream>>>(t2_w, t3_w, t4_w, fus_w, w16);
    sampup_k<<<512, 256, 0, stream>>>(x, sample_w, up_w, up_b, r_all);

    const size_t LDSB = 49920;
    _Float16* feat = fA;
    _Float16* feat_alt = fB;

    for (int m = 0; m < 8; ++m) {
        if (m == 0) {
            h1_k<<<256, 256, 0, stream>>>(r_all + m * NPIX, h1_w + m * 64 * 9,
                                          h1_b + m * 64, h1_a + m, feat);
        } else {
            h1_k<<<256, 256, 0, stream>>>(r_all + m * NPIX, h1_w + m * 64 * 9,
                                          h1_b + m * 64, h1_a + m, hb);
            conv_mfma_k<2><<<512, 256, LDSB, stream>>>(
                feat, hb, wblk(24 + (m - 1) * 2), wblk(24 + (m - 1) * 2 + 1),
                fus_b + (m - 1) * 64, fus_a + (m - 1), feat_alt);
            _Float16* tmp = feat; feat = feat_alt; feat_alt = tmp;
        }
        conv_mfma_k<1><<<512, 256, LDSB, stream>>>(
            feat, nullptr, wblk(m), nullptr, t2_b + m * 64, t2_a + m, t1);
        conv_mfma_k<1><<<512, 256, LDSB, stream>>>(
            t1, nullptr, wblk(8 + m), nullptr, t3_b + m * 64, t3_a + m, t2b);
        conv_mfma_k<1><<<512, 256, LDSB, stream>>>(
            t2b, nullptr, wblk(16 + m), nullptr, t4_b + m * 64, t4_a + m, t1);
        t5_k<<<256, 256, 0, stream>>>(t1, t5_w + (size_t)m * 64 * 9,
                                      t5_b + m, out + m * NPIX);
    }
}

// Round 4
// 875.011 us; speedup vs baseline: 15.4911x; 1.1420x over previous
//
#include <hip/hip_runtime.h>

// HierarchicalCSNet — f16 MFMA implicit-GEMM, A-from-global, padded planes.
// Feature planes: padded NHWC f16 [258][258][64], borders zero (= conv pad).
// conv3x3: block = 4 waves, tile 64co x 128px (half row), grid 512, 3 blk/CU.
//   LDS: input halo only [3][130][8ch][8] f16 = 49.9KB.
//   Staging via global_load_lds (linear dest, pre-swizzled global source).
//   A (weights) loaded per-wave from global layout [tap][kk][h][co][8] (L2-hot).
constexpr int H = 256, W = 256, NPIX = H * W;
constexpr int PW = 258;
constexpr size_t PLANE = (size_t)PW * PW * 64;      // f16 elements

typedef _Float16 half8 __attribute__((ext_vector_type(8)));
typedef _Float16 half4 __attribute__((ext_vector_type(4)));
typedef float    f32x4 __attribute__((ext_vector_type(4)));
typedef float    f32x16 __attribute__((ext_vector_type(16)));

__device__ __forceinline__ void gl16(const _Float16* g, _Float16* l)
{
    __builtin_amdgcn_global_load_lds(
        (const __attribute__((address_space(1))) unsigned int*)g,
        (__attribute__((address_space(3))) unsigned int*)l, 16, 0, 0);
}

// ---------------------------------------------------- border zero (5 planes)
__global__ __launch_bounds__(256)
void border_k(_Float16* __restrict__ planes)
{
    int tid = blockIdx.x * 256 + threadIdx.x;
    if (tid >= 5 * 1028 * 8) return;
    int c = tid & 7, rem = tid >> 3;
    int p = rem / 1028, b = rem % 1028;
    int gy, gx;
    if (b < 258)      { gy = 0;           gx = b; }
    else if (b < 516) { gy = 257;         gx = b - 258; }
    else if (b < 772) { gy = b - 516 + 1; gx = 0; }
    else              { gy = b - 772 + 1; gx = 257; }
    f32x4 z = {0.f, 0.f, 0.f, 0.f};
    *(f32x4*)(planes + (size_t)p * PLANE + ((size_t)(gy * PW + gx) * 64) + c * 8) = z;
}

// --------------------------- fused sampling + up(1x1) + reshape_adap (all m)
__global__ __launch_bounds__(256)
void sampup_k(const float* __restrict__ x, const float* __restrict__ sw,
              const float* __restrict__ uw, const float* __restrict__ ub,
              float* __restrict__ r_all)
{
    int m = blockIdx.x >> 6, ij = blockIdx.x & 63;
    int i = ij >> 3, j = ij & 7;
    __shared__ float s_lds[16];
    int t = threadIdx.x;
    if (t < 208) {
        int c = t >> 4, sub = t & 15;
        float acc = 0.f;
        for (int k = sub * 64; k < sub * 64 + 64; ++k) {
            int p = k >> 5, q = k & 31;
            acc += x[(i * 32 + p) * W + (j * 32 + q)] * sw[(m * 13 + c) * 1024 + k];
        }
        #pragma unroll
        for (int off = 8; off; off >>= 1) acc += __shfl_down(acc, off, 16);
        if (sub == 0) s_lds[c] = acc;
    }
    __syncthreads();
    const float* uwm = uw + m * 1024 * 13;
    float* rm = r_all + m * NPIX;
    #pragma unroll
    for (int pi = 0; pi < 4; ++pi) {
        int px = pi * 256 + t;
        int p = px >> 5, q = px & 31;
        int oc = p * 32 + q;
        float acc = ub[m * 1024 + oc];
        #pragma unroll
        for (int c = 0; c < 13; ++c) acc = fmaf(uwm[oc * 13 + c], s_lds[c], acc);
        rm[((i * 32 + p) << 8) + j * 32 + q] = acc;
    }
}

// --------------------------------------- h1: conv 1->64, writes padded plane
// grid 1024: y = bid>>2, x-quarter = bid&3. thread: px = t&63, co-group = t>>6
// (wave-uniform -> scalar weight loads).
__global__ __launch_bounds__(256)
void h1_k(const float* __restrict__ r, const float* __restrict__ w,
          const float* __restrict__ b, const float* __restrict__ a,
          _Float16* __restrict__ out)
{
    const int t = threadIdx.x;
    const int px = t & 63, cog = t >> 6;
    const int y = blockIdx.x >> 2;
    const int x = ((blockIdx.x & 3) << 6) + px;
    float v[9];
    #pragma unroll
    for (int dy = 0; dy < 3; ++dy) {
        int gy = y + dy - 1;
        #pragma unroll
        for (int dx = 0; dx < 3; ++dx) {
            int gx = x + dx - 1;
            v[dy*3+dx] = ((unsigned)gy < 256u && (unsigned)gx < 256u)
                       ? r[(gy << 8) + gx] : 0.f;
        }
    }
    const float slope = a[0];
    _Float16* op = out + ((size_t)((y + 1) * PW + (x + 1))) * 64 + cog * 16;
    #pragma unroll
    for (int cg2 = 0; cg2 < 2; ++cg2) {
        half8 o;
        #pragma unroll
        for (int j = 0; j < 8; ++j) {
            int co = cog * 16 + cg2 * 8 + j;
            float acc = b[co];
            #pragma unroll
            for (int k = 0; k < 9; ++k) acc = fmaf(v[k], w[co*9+k], acc);
            acc = acc >= 0.f ? acc : slope * acc;
            o[j] = (_Float16)acc;
        }
        *(half8*)(op + cg2 * 8) = o;
    }
}

// ------- weight prep: fp32 [co][ci][9] -> f16 [blk][tap][kk][h][co][8]
// ci = (kk*2+h)*8+e. blocks 0-7: t2, 8-15: t3, 16-23: t4, 24+2f+half: fusion.
__global__ __launch_bounds__(256)
void wprep_k(const float* __restrict__ t2w, const float* __restrict__ t3w,
             const float* __restrict__ t4w, const float* __restrict__ fusw,
             _Float16* __restrict__ w16)
{
    int tid = blockIdx.x * 256 + threadIdx.x;
    if (tid >= 38 * 36864) return;
    int blk = tid / 36864, r2 = tid % 36864;
    int e = r2 & 7, co = (r2 >> 3) & 63, hh = (r2 >> 9) & 1, kk = (r2 >> 10) & 3,
        tap = r2 >> 12;
    const float* src; int cin, cib;
    if (blk < 24) {
        int which = blk >> 3, m = blk & 7;
        src = (which == 0 ? t2w : which == 1 ? t3w : t4w) + (size_t)m * 64 * 64 * 9;
        cin = 64; cib = 0;
    } else {
        int f = (blk - 24) >> 1; cib = ((blk - 24) & 1) * 64;
        src = fusw + (size_t)f * 64 * 128 * 9; cin = 128;
    }
    int ci = cib + (kk * 2 + hh) * 8 + e;
    w16[tid] = (_Float16)src[((size_t)co * cin + ci) * 9 + tap];
}

// ---------------------------------------------- MFMA conv3x3 (64 ci / pass)
template <int PASSES>
__global__ __launch_bounds__(256, 3)
void conv_mfma_k(const _Float16* __restrict__ in0, const _Float16* __restrict__ in1,
                 const _Float16* __restrict__ w0, const _Float16* __restrict__ w1,
                 const float* __restrict__ bias, const float* __restrict__ alpha,
                 _Float16* __restrict__ out)
{
    const int lane = threadIdx.x & 63;
    const int wv   = threadIdx.x >> 6;
    const int y    = blockIdx.x >> 1;
    const int x0   = (blockIdx.x & 1) * 128;
    const int p0   = wv * 32;
    const int h    = lane >> 5;
    const int cl   = lane & 31;

    extern __shared__ __align__(16) char smem[];
    _Float16* li = (_Float16*)smem;           // [3][130][8][8] = 49920 B

    f32x16 acc0, acc1;
    #pragma unroll
    for (int q = 0; q < 4; ++q)
        #pragma unroll
        for (int j = 0; j < 4; ++j) {
            int co = q * 8 + 4 * h + j;
            acc0[q*4+j] = bias[co];
            acc1[q*4+j] = bias[co + 32];
        }

    #pragma unroll
    for (int pass = 0; pass < PASSES; ++pass) {
        const _Float16* in   = pass ? in1 : in0;
        const _Float16* wsrc = pass ? w1 : w0;
        if (pass) __syncthreads();            // LDS reuse fence
        // stage [3][130][8] chunks = 3120; wave wv: chunks [wv*780, wv*780+780)
        {
            const int base = wv * 780;
            #pragma unroll
            for (int i = 0; i < 13; ++i) {
                int Lc = base + i * 64 + lane;
                int r = Lc / 1040, rem = Lc % 1040;
                int px = rem >> 3, c = rem & 7;
                const _Float16* src = in +
                    ((size_t)((y + r) * PW + (x0 + px)) * 64 + (c ^ (px & 7)) * 8);
                _Float16* dst = li + (size_t)(base + i * 64) * 8;
                if (i < 12 || lane < 12) gl16(src, dst);
            }
        }
        __syncthreads();                      // drains vmcnt before reads
        // compute: 9 taps x 4 K-chunks x 2 co-tiles; A from global (L2-hot)
        #pragma unroll
        for (int tap = 0; tap < 9; ++tap) {
            const int dy = tap / 3;
            const int pxl = p0 + cl + tap % 3;
            #pragma unroll
            for (int kk = 0; kk < 4; ++kk) {
                const int c = kk * 2 + h;
                half8 a0 = *(const half8*)(wsrc + ((size_t)(((tap*4+kk)*2+h)*64 + cl) * 8));
                half8 a1 = *(const half8*)(wsrc + ((size_t)(((tap*4+kk)*2+h)*64 + 32 + cl) * 8));
                half8 bf = *(const half8*)(li + ((size_t)((dy*130 + pxl)*8 + (c ^ (pxl & 7))) * 8));
                acc0 = __builtin_amdgcn_mfma_f32_32x32x16_f16(a0, bf, acc0, 0, 0, 0);
                acc1 = __builtin_amdgcn_mfma_f32_32x32x16_f16(a1, bf, acc1, 0, 0, 0);
            }
        }
    }
    // store: D col=lane&31=px, row=(r&3)+8*(r>>2)+4*h=co ; padded interior
    const float slope = alpha[0];
    const size_t gp = (size_t)((y + 1) * PW + (x0 + p0 + cl + 1)) * 64;
    #pragma unroll
    for (int q = 0; q < 4; ++q) {
        half4 v0, v1;
        #pragma unroll
        for (int j = 0; j < 4; ++j) {
            float xv = acc0[q*4+j]; xv = xv >= 0.f ? xv : slope * xv; v0[j] = (_Float16)xv;
            float yv = acc1[q*4+j]; yv = yv >= 0.f ? yv : slope * yv; v1[j] = (_Float16)yv;
        }
        int co0 = q * 8 + 4 * h;
        *(half4*)(out + gp + co0)      = v0;
        *(half4*)(out + gp + co0 + 32) = v1;
    }
}

// ------------------------------------------ t5: conv 64->1 (padded input)
// grid 2048: y = bid>>3, x-block = bid&7 (32 px). thread: px = t&31, cg = t>>5.
// Channel-split + shfl/LDS reduce; weights staged in LDS.
__global__ __launch_bounds__(256)
void t5_k(const _Float16* __restrict__ in, const float* __restrict__ w,
          const float* __restrict__ b, float* __restrict__ out)
{
    const int t = threadIdx.x;
    const int lane = t & 63, wv = t >> 6;
    const int px = t & 31, cg = t >> 5;
    const int y  = blockIdx.x >> 3;
    const int x0 = (blockIdx.x & 7) << 5;
    const int x  = x0 + px;

    __shared__ float wl[576];
    __shared__ float part[4][32];
    #pragma unroll
    for (int i = 0; i < 3; ++i) {
        int idx = i * 256 + t;
        if (idx < 576) wl[idx] = w[idx];
    }
    __syncthreads();

    float acc = 0.f;
    #pragma unroll
    for (int dy = 0; dy < 3; ++dy)
        #pragma unroll
        for (int dx = 0; dx < 3; ++dx) {
            half8 vv = *(const half8*)(in + (size_t)((y + dy) * PW + (x + dx)) * 64 + cg * 8);
            int tap = dy * 3 + dx;
            #pragma unroll
            for (int e = 0; e < 8; ++e)
                acc = fmaf((float)vv[e], wl[(cg * 8 + e) * 9 + tap], acc);
        }
    acc += __shfl_xor(acc, 32, 64);
    if (lane < 32) part[wv][lane] = acc;
    __syncthreads();
    if (t < 32) {
        float s = part[0][t] + part[1][t] + part[2][t] + part[3][t] + b[0];
        out[(y << 8) + x0 + t] = s;
    }
}

extern "C" void kernel_launch(void* const* d_in, const int* in_sizes, int n_in,
                              void* d_out, int out_size, void* d_ws, size_t ws_size,
                              hipStream_t stream)
{
    const float* x        = (const float*)d_in[0];
    const float* sample_w = (const float*)d_in[1];
    const float* up_w     = (const float*)d_in[2];
    const float* up_b     = (const float*)d_in[3];
    const float* h1_w     = (const float*)d_in[4];
    const float* h1_b     = (const float*)d_in[5];
    const float* h1_a     = (const float*)d_in[6];
    const float* fus_w    = (const float*)d_in[7];
    const float* fus_b    = (const float*)d_in[8];
    const float* fus_a    = (const float*)d_in[9];
    const float* t2_w     = (const float*)d_in[10];
    const float* t2_b     = (const float*)d_in[11];
    const float* t2_a     = (const float*)d_in[12];
    const float* t3_w     = (const float*)d_in[13];
    const float* t3_b     = (const float*)d_in[14];
    const float* t3_a     = (const float*)d_in[15];
    const float* t4_w     = (const float*)d_in[16];
    const float* t4_b     = (const float*)d_in[17];
    const float* t4_a     = (const float*)d_in[18];
    const float* t5_w     = (const float*)d_in[19];
    const float* t5_b     = (const float*)d_in[20];

    float* out = (float*)d_out;
    char*  wsb = (char*)d_ws;

    _Float16* w16    = (_Float16*)wsb;                        // 2,801,664 B
    float*    r_all  = (float*)(wsb + 2801664);               // 2,097,152 B
    _Float16* planes = (_Float16*)(wsb + 4898816);            // 5 x 8,520,192 B

    _Float16* fA  = planes;
    _Float16* fB  = planes + PLANE;
    _Float16* hb  = planes + 2 * PLANE;
    _Float16* t1  = planes + 3 * PLANE;
    _Float16* t2b = planes + 4 * PLANE;

    auto wblk = [&](int b) { return w16 + (size_t)b * 36864; };

    border_k<<<161, 256, 0, stream>>>(planes);
    wprep_k<<<5472, 256, 0, stream>>>(t2_w, t3_w, t4_w, fus_w, w16);
    sampup_k<<<512, 256, 0, stream>>>(x, sample_w, up_w, up_b, r_all);

    const size_t LDSB = 49920;
    _Float16* feat = fA;
    _Float16* feat_alt = fB;

    for (int m = 0; m < 8; ++m) {
        if (m == 0) {
            h1_k<<<1024, 256, 0, stream>>>(r_all + m * NPIX, h1_w + m * 64 * 9,
                                           h1_b + m * 64, h1_a + m, feat);
        } else {
            h1_k<<<1024, 256, 0, stream>>>(r_all + m * NPIX, h1_w + m * 64 * 9,
                                           h1_b + m * 64, h1_a + m, hb);
            conv_mfma_k<2><<<512, 256, LDSB, stream>>>(
                feat, hb, wblk(24 + (m - 1) * 2), wblk(24 + (m - 1) * 2 + 1),
                fus_b + (m - 1) * 64, fus_a + (m - 1), feat_alt);
            _Float16* tmp = feat; feat = feat_alt; feat_alt = tmp;
        }
        conv_mfma_k<1><<<512, 256, LDSB, stream>>>(
            feat, nullptr, wblk(m), nullptr, t2_b + m * 64, t2_a + m, t1);
        conv_mfma_k<1><<<512, 256, LDSB, stream>>>(
            t1, nullptr, wblk(8 + m), nullptr, t3_b + m * 64, t3_a + m, t2b);
        conv_mfma_k<1><<<512, 256, LDSB, stream>>>(
            t2b, nullptr, wblk(16 + m), nullptr, t4_b + m * 64, t4_a + m, t1);
        t5_k<<<2048, 256, 0, stream>>>(t1, t5_w + (size_t)m * 64 * 9,
                                       t5_b + m, out + m * NPIX);
    }
}

// Round 5
// 582.245 us; speedup vs baseline: 23.2803x; 1.5028x over previous
//
#include <hip/hip_runtime.h>

// HierarchicalCSNet — f16 MFMA implicit-GEMM, full-row blocks, LDS-shared A.
// Feature planes: padded NHWC f16 [258][258][64], borders zero (= conv pad).
// conv3x3: block = 4 waves, tile 64co x 256px (full row), grid 256, 1 blk/CU.
//   Wave: 64 px as 2 subtiles sharing A-fragments (4 MFMA per 2A+2B LDS reads).
//   LDS: halo [3][258][8][8] f16 = 99072 B + weight buf 40960 B (2-part stage).
//   y = (bid&7)*32 + bid>>3  -> XCD-contiguous row bands (halo L2 reuse).
constexpr int H = 256, W = 256, NPIX = H * W;
constexpr int PW = 258;
constexpr size_t PLANE = (size_t)PW * PW * 64;      // f16 elements

typedef _Float16 half8 __attribute__((ext_vector_type(8)));
typedef _Float16 half4 __attribute__((ext_vector_type(4)));
typedef float    f32x4 __attribute__((ext_vector_type(4)));
typedef float    f32x16 __attribute__((ext_vector_type(16)));

__device__ __forceinline__ void gl16(const _Float16* g, _Float16* l)
{
    __builtin_amdgcn_global_load_lds(
        (const __attribute__((address_space(1))) unsigned int*)g,
        (__attribute__((address_space(3))) unsigned int*)l, 16, 0, 0);
}

// ---------------------------------------------------- border zero (5 planes)
__global__ __launch_bounds__(256)
void border_k(_Float16* __restrict__ planes)
{
    int tid = blockIdx.x * 256 + threadIdx.x;
    if (tid >= 5 * 1028 * 8) return;
    int c = tid & 7, rem = tid >> 3;
    int p = rem / 1028, b = rem % 1028;
    int gy, gx;
    if (b < 258)      { gy = 0;           gx = b; }
    else if (b < 516) { gy = 257;         gx = b - 258; }
    else if (b < 772) { gy = b - 516 + 1; gx = 0; }
    else              { gy = b - 772 + 1; gx = 257; }
    f32x4 z = {0.f, 0.f, 0.f, 0.f};
    *(f32x4*)(planes + (size_t)p * PLANE + ((size_t)(gy * PW + gx) * 64) + c * 8) = z;
}

// --------------------------- fused sampling + up(1x1) + reshape_adap (all m)
__global__ __launch_bounds__(256)
void sampup_k(const float* __restrict__ x, const float* __restrict__ sw,
              const float* __restrict__ uw, const float* __restrict__ ub,
              float* __restrict__ r_all)
{
    int m = blockIdx.x >> 6, ij = blockIdx.x & 63;
    int i = ij >> 3, j = ij & 7;
    __shared__ float s_lds[16];
    int t = threadIdx.x;
    if (t < 208) {
        int c = t >> 4, sub = t & 15;
        float acc = 0.f;
        for (int k = sub * 64; k < sub * 64 + 64; ++k) {
            int p = k >> 5, q = k & 31;
            acc += x[(i * 32 + p) * W + (j * 32 + q)] * sw[(m * 13 + c) * 1024 + k];
        }
        #pragma unroll
        for (int off = 8; off; off >>= 1) acc += __shfl_down(acc, off, 16);
        if (sub == 0) s_lds[c] = acc;
    }
    __syncthreads();
    const float* uwm = uw + m * 1024 * 13;
    float* rm = r_all + m * NPIX;
    #pragma unroll
    for (int pi = 0; pi < 4; ++pi) {
        int px = pi * 256 + t;
        int p = px >> 5, q = px & 31;
        int oc = p * 32 + q;
        float acc = ub[m * 1024 + oc];
        #pragma unroll
        for (int c = 0; c < 13; ++c) acc = fmaf(uwm[oc * 13 + c], s_lds[c], acc);
        rm[((i * 32 + p) << 8) + j * 32 + q] = acc;
    }
}

// --------------------------------------- h1: conv 1->64, writes padded plane
__global__ __launch_bounds__(256)
void h1_k(const float* __restrict__ r, const float* __restrict__ w,
          const float* __restrict__ b, const float* __restrict__ a,
          _Float16* __restrict__ out)
{
    const int t = threadIdx.x;
    const int px = t & 63, cog = t >> 6;
    const int y = blockIdx.x >> 2;
    const int x = ((blockIdx.x & 3) << 6) + px;
    float v[9];
    #pragma unroll
    for (int dy = 0; dy < 3; ++dy) {
        int gy = y + dy - 1;
        #pragma unroll
        for (int dx = 0; dx < 3; ++dx) {
            int gx = x + dx - 1;
            v[dy*3+dx] = ((unsigned)gy < 256u && (unsigned)gx < 256u)
                       ? r[(gy << 8) + gx] : 0.f;
        }
    }
    const float slope = a[0];
    _Float16* op = out + ((size_t)((y + 1) * PW + (x + 1))) * 64 + cog * 16;
    #pragma unroll
    for (int cg2 = 0; cg2 < 2; ++cg2) {
        half8 o;
        #pragma unroll
        for (int j = 0; j < 8; ++j) {
            int co = cog * 16 + cg2 * 8 + j;
            float acc = b[co];
            #pragma unroll
            for (int k = 0; k < 9; ++k) acc = fmaf(v[k], w[co*9+k], acc);
            acc = acc >= 0.f ? acc : slope * acc;
            o[j] = (_Float16)acc;
        }
        *(half8*)(op + cg2 * 8) = o;
    }
}

// ------- weight prep: fp32 [co][ci][9] -> f16 [blk][tap][kk][h][co][8]
// ci = (kk*2+h)*8+e. blocks 0-7: t2, 8-15: t3, 16-23: t4, 24+2f+half: fusion.
__global__ __launch_bounds__(256)
void wprep_k(const float* __restrict__ t2w, const float* __restrict__ t3w,
             const float* __restrict__ t4w, const float* __restrict__ fusw,
             _Float16* __restrict__ w16)
{
    int tid = blockIdx.x * 256 + threadIdx.x;
    if (tid >= 38 * 36864) return;
    int blk = tid / 36864, r2 = tid % 36864;
    int e = r2 & 7, co = (r2 >> 3) & 63, hh = (r2 >> 9) & 1, kk = (r2 >> 10) & 3,
        tap = r2 >> 12;
    const float* src; int cin, cib;
    if (blk < 24) {
        int which = blk >> 3, m = blk & 7;
        src = (which == 0 ? t2w : which == 1 ? t3w : t4w) + (size_t)m * 64 * 64 * 9;
        cin = 64; cib = 0;
    } else {
        int f = (blk - 24) >> 1; cib = ((blk - 24) & 1) * 64;
        src = fusw + (size_t)f * 64 * 128 * 9; cin = 128;
    }
    int ci = cib + (kk * 2 + hh) * 8 + e;
    w16[tid] = (_Float16)src[((size_t)co * cin + ci) * 9 + tap];
}

// ------------------------------- compute NT taps starting at T0 (weights in
// lw hold taps T0..T0+NT-1 contiguously)
template <int NT>
__device__ __forceinline__ void conv_taps(
    const _Float16* __restrict__ li, const _Float16* __restrict__ lw,
    int T0, int px0, int cl, int h,
    f32x16& acc00, f32x16& acc01, f32x16& acc10, f32x16& acc11)
{
    #pragma unroll
    for (int tt = 0; tt < NT; ++tt) {
        const int tap = T0 + tt;
        const int dy = tap / 3, dx = tap % 3;
        const int hx0 = px0 + cl + dx;
        const int hx1 = hx0 + 32;
        const int sw8 = hx0 & 7;               // same for hx1 (hx1 = hx0+32)
        #pragma unroll
        for (int kk = 0; kk < 4; ++kk) {
            const int c = kk * 2 + h;
            half8 a0 = *(const half8*)(lw + ((size_t)(((tt*4+kk)*2+h)*64 + cl)) * 8);
            half8 a1 = *(const half8*)(lw + ((size_t)(((tt*4+kk)*2+h)*64 + 32 + cl)) * 8);
            half8 b0 = *(const half8*)(li + ((size_t)((dy*258 + hx0)*8 + (c ^ sw8))) * 8);
            half8 b1 = *(const half8*)(li + ((size_t)((dy*258 + hx1)*8 + (c ^ sw8))) * 8);
            acc00 = __builtin_amdgcn_mfma_f32_32x32x16_f16(a0, b0, acc00, 0, 0, 0);
            acc01 = __builtin_amdgcn_mfma_f32_32x32x16_f16(a0, b1, acc01, 0, 0, 0);
            acc10 = __builtin_amdgcn_mfma_f32_32x32x16_f16(a1, b0, acc10, 0, 0, 0);
            acc11 = __builtin_amdgcn_mfma_f32_32x32x16_f16(a1, b1, acc11, 0, 0, 0);
        }
    }
}

// ---------------------------------------------- MFMA conv3x3 (64 ci / pass)
template <int PASSES>
__global__ __launch_bounds__(256, 1)
void conv_mfma_k(const _Float16* __restrict__ in0, const _Float16* __restrict__ in1,
                 const _Float16* __restrict__ w0, const _Float16* __restrict__ w1,
                 const float* __restrict__ bias, const float* __restrict__ alpha,
                 _Float16* __restrict__ out)
{
    const int t    = threadIdx.x;
    const int lane = t & 63;
    const int wv   = t >> 6;
    const int bid  = blockIdx.x;
    const int y    = ((bid & 7) << 5) + (bid >> 3);   // XCD row-band mapping
    const int h    = lane >> 5;
    const int cl   = lane & 31;
    const int px0  = wv * 64;

    extern __shared__ __align__(16) char smem[];
    _Float16* li = (_Float16*)smem;              // [3][258][8][8]  99072 B
    _Float16* lw = (_Float16*)(smem + 99072);    // [<=5][4][2][64][8] 40960 B

    f32x16 acc00, acc01, acc10, acc11;
    #pragma unroll
    for (int q = 0; q < 4; ++q)
        #pragma unroll
        for (int j = 0; j < 4; ++j) {
            int co = q * 8 + 4 * h + j;
            float b0 = bias[co], b1 = bias[co + 32];
            acc00[q*4+j] = b0; acc01[q*4+j] = b0;
            acc10[q*4+j] = b1; acc11[q*4+j] = b1;
        }

    #pragma unroll
    for (int pass = 0; pass < PASSES; ++pass) {
        const _Float16* in   = pass ? in1 : in0;
        const _Float16* wsrc = pass ? w1 : w0;
        if (pass) __syncthreads();               // LDS reuse fence
        // stage halo: 3*258*8 = 6192 chunks, pre-swizzled global source
        #pragma unroll
        for (int i = 0; i < 25; ++i) {
            int f = i * 256 + t;
            if (f < 6192) {
                int r = f / 2064, rem = f % 2064;
                int hx = rem >> 3, c = rem & 7;
                const _Float16* src = in + ((size_t)((y + r) * PW + hx) * 64
                                            + (c ^ (hx & 7)) * 8);
                gl16(src, li + (size_t)f * 8);
            }
        }
        // stage weights taps 0..4 : 2560 chunks (linear)
        #pragma unroll
        for (int i = 0; i < 10; ++i) {
            int ch = i * 256 + t;
            gl16(wsrc + (size_t)ch * 8, lw + (size_t)ch * 8);
        }
        __syncthreads();                         // drains vmcnt
        conv_taps<5>(li, lw, 0, px0, cl, h, acc00, acc01, acc10, acc11);
        __syncthreads();                         // all reads of lw done
        // stage weights taps 5..8 : 2048 chunks
        #pragma unroll
        for (int i = 0; i < 8; ++i) {
            int ch = i * 256 + t;
            gl16(wsrc + (size_t)(2560 + ch) * 8, lw + (size_t)ch * 8);
        }
        __syncthreads();
        conv_taps<4>(li, lw, 5, px0, cl, h, acc00, acc01, acc10, acc11);
    }

    // store: D col=lane&31=px, row=(r&3)+8*(r>>2)+4*h=co ; padded interior
    const float slope = alpha[0];
    #pragma unroll
    for (int pt = 0; pt < 2; ++pt) {
        const size_t gp = (size_t)((y + 1) * PW + (px0 + pt * 32 + cl + 1)) * 64;
        const f32x16& A0 = pt ? acc01 : acc00;
        const f32x16& A1 = pt ? acc11 : acc10;
        #pragma unroll
        for (int q = 0; q < 4; ++q) {
            half4 v0, v1;
            #pragma unroll
            for (int j = 0; j < 4; ++j) {
                float xv = A0[q*4+j]; xv = xv >= 0.f ? xv : slope * xv; v0[j] = (_Float16)xv;
                float yv = A1[q*4+j]; yv = yv >= 0.f ? yv : slope * yv; v1[j] = (_Float16)yv;
            }
            int co0 = q * 8 + 4 * h;
            *(half4*)(out + gp + co0)      = v0;
            *(half4*)(out + gp + co0 + 32) = v1;
        }
    }
}

// ------------------------------------------ t5: conv 64->1 (padded input)
__global__ __launch_bounds__(256)
void t5_k(const _Float16* __restrict__ in, const float* __restrict__ w,
          const float* __restrict__ b, float* __restrict__ out)
{
    const int t = threadIdx.x;
    const int lane = t & 63, wv = t >> 6;
    const int px = t & 31, cg = t >> 5;
    const int y  = blockIdx.x >> 3;
    const int x0 = (blockIdx.x & 7) << 5;
    const int x  = x0 + px;

    __shared__ float wl[576];
    __shared__ float part[4][32];
    #pragma unroll
    for (int i = 0; i < 3; ++i) {
        int idx = i * 256 + t;
        if (idx < 576) wl[idx] = w[idx];
    }
    __syncthreads();

    float acc = 0.f;
    #pragma unroll
    for (int dy = 0; dy < 3; ++dy)
        #pragma unroll
        for (int dx = 0; dx < 3; ++dx) {
            half8 vv = *(const half8*)(in + (size_t)((y + dy) * PW + (x + dx)) * 64 + cg * 8);
            int tap = dy * 3 + dx;
            #pragma unroll
            for (int e = 0; e < 8; ++e)
                acc = fmaf((float)vv[e], wl[(cg * 8 + e) * 9 + tap], acc);
        }
    acc += __shfl_xor(acc, 32, 64);
    if (lane < 32) part[wv][lane] = acc;
    __syncthreads();
    if (t < 32) {
        float s = part[0][t] + part[1][t] + part[2][t] + part[3][t] + b[0];
        out[(y << 8) + x0 + t] = s;
    }
}

extern "C" void kernel_launch(void* const* d_in, const int* in_sizes, int n_in,
                              void* d_out, int out_size, void* d_ws, size_t ws_size,
                              hipStream_t stream)
{
    const float* x        = (const float*)d_in[0];
    const float* sample_w = (const float*)d_in[1];
    const float* up_w     = (const float*)d_in[2];
    const float* up_b     = (const float*)d_in[3];
    const float* h1_w     = (const float*)d_in[4];
    const float* h1_b     = (const float*)d_in[5];
    const float* h1_a     = (const float*)d_in[6];
    const float* fus_w    = (const float*)d_in[7];
    const float* fus_b    = (const float*)d_in[8];
    const float* fus_a    = (const float*)d_in[9];
    const float* t2_w     = (const float*)d_in[10];
    const float* t2_b     = (const float*)d_in[11];
    const float* t2_a     = (const float*)d_in[12];
    const float* t3_w     = (const float*)d_in[13];
    const float* t3_b     = (const float*)d_in[14];
    const float* t3_a     = (const float*)d_in[15];
    const float* t4_w     = (const float*)d_in[16];
    const float* t4_b     = (const float*)d_in[17];
    const float* t4_a     = (const float*)d_in[18];
    const float* t5_w     = (const float*)d_in[19];
    const float* t5_b     = (const float*)d_in[20];

    float* out = (float*)d_out;
    char*  wsb = (char*)d_ws;

    _Float16* w16    = (_Float16*)wsb;                        // 2,801,664 B
    float*    r_all  = (float*)(wsb + 2801664);               // 2,097,152 B
    _Float16* planes = (_Float16*)(wsb + 4898816);            // 5 x 8,520,192 B

    _Float16* fA  = planes;
    _Float16* fB  = planes + PLANE;
    _Float16* hb  = planes + 2 * PLANE;
    _Float16* t1  = planes + 3 * PLANE;
    _Float16* t2b = planes + 4 * PLANE;

    auto wblk = [&](int b) { return w16 + (size_t)b * 36864; };

    border_k<<<161, 256, 0, stream>>>(planes);
    wprep_k<<<5472, 256, 0, stream>>>(t2_w, t3_w, t4_w, fus_w, w16);
    sampup_k<<<512, 256, 0, stream>>>(x, sample_w, up_w, up_b, r_all);

    const size_t LDSB = 99072 + 40960;           // 140032 B
    _Float16* feat = fA;
    _Float16* feat_alt = fB;

    for (int m = 0; m < 8; ++m) {
        if (m == 0) {
            h1_k<<<1024, 256, 0, stream>>>(r_all + m * NPIX, h1_w + m * 64 * 9,
                                           h1_b + m * 64, h1_a + m, feat);
        } else {
            h1_k<<<1024, 256, 0, stream>>>(r_all + m * NPIX, h1_w + m * 64 * 9,
                                           h1_b + m * 64, h1_a + m, hb);
            conv_mfma_k<2><<<256, 256, LDSB, stream>>>(
                feat, hb, wblk(24 + (m - 1) * 2), wblk(24 + (m - 1) * 2 + 1),
                fus_b + (m - 1) * 64, fus_a + (m - 1), feat_alt);
            _Float16* tmp = feat; feat = feat_alt; feat_alt = tmp;
        }
        conv_mfma_k<1><<<256, 256, LDSB, stream>>>(
            feat, nullptr, wblk(m), nullptr, t2_b + m * 64, t2_a + m, t1);
        conv_mfma_k<1><<<256, 256, LDSB, stream>>>(
            t1, nullptr, wblk(8 + m), nullptr, t3_b + m * 64, t3_a + m, t2b);
        conv_mfma_k<1><<<256, 256, LDSB, stream>>>(
            t2b, nullptr, wblk(16 + m), nullptr, t4_b + m * 64, t4_a + m, t1);
        t5_k<<<2048, 256, 0, stream>>>(t1, t5_w + (size_t)m * 64 * 9,
                                       t5_b + m, out + m * NPIX);
    }
}

// Round 6
// 459.905 us; speedup vs baseline: 29.4732x; 1.2660x over previous
//
#include <hip/hip_runtime.h>

// HierarchicalCSNet — f16 MFMA implicit-GEMM, 2-wave blocks, batched stages.
// Feature planes: padded NHWC f16 [258][258][64], borders zero (= conv pad).
// conv3x3: block = 2 waves (128 thr), tile 64co x 128px (half row).
//   LDS: halo [3][130][8][8] = 49920 B + weight buf (3 taps) 24576 B = 74.5 KB
//   -> 2 blocks/CU resident; stage/compute phases of the two blocks overlap.
//   Weights staged per 3-tap group; A shared across 2 px-subtiles per wave.
// Schedule: border/wprep/sampup -> h1-all -> 7x fusion (serial) ->
//   t2-all -> t3-all -> t4-all -> t5-all   (15 dispatches total).
constexpr int H = 256, W = 256, NPIX = H * W;
constexpr int PW = 258;
constexpr size_t PLANE = (size_t)PW * PW * 64;      // f16 elements per plane

typedef _Float16 half8 __attribute__((ext_vector_type(8)));
typedef _Float16 half4 __attribute__((ext_vector_type(4)));
typedef float    f32x4 __attribute__((ext_vector_type(4)));
typedef float    f32x16 __attribute__((ext_vector_type(16)));

__device__ __forceinline__ void gl16(const _Float16* g, _Float16* l)
{
    __builtin_amdgcn_global_load_lds(
        (const __attribute__((address_space(1))) unsigned int*)g,
        (__attribute__((address_space(3))) unsigned int*)l, 16, 0, 0);
}

// --------------------------------------------------- border zero (24 planes)
__global__ __launch_bounds__(256)
void border_k(_Float16* __restrict__ planes)
{
    int tid = blockIdx.x * 256 + threadIdx.x;
    if (tid >= 24 * 1028 * 8) return;
    int c = tid & 7, rem = tid >> 3;
    int p = rem / 1028, b = rem % 1028;
    int gy, gx;
    if (b < 258)      { gy = 0;           gx = b; }
    else if (b < 516) { gy = 257;         gx = b - 258; }
    else if (b < 772) { gy = b - 516 + 1; gx = 0; }
    else              { gy = b - 772 + 1; gx = 257; }
    f32x4 z = {0.f, 0.f, 0.f, 0.f};
    *(f32x4*)(planes + (size_t)p * PLANE + ((size_t)(gy * PW + gx) * 64) + c * 8) = z;
}

// --------------------------- fused sampling + up(1x1) + reshape_adap (all m)
__global__ __launch_bounds__(256)
void sampup_k(const float* __restrict__ x, const float* __restrict__ sw,
              const float* __restrict__ uw, const float* __restrict__ ub,
              float* __restrict__ r_all)
{
    int m = blockIdx.x >> 6, ij = blockIdx.x & 63;
    int i = ij >> 3, j = ij & 7;
    __shared__ float s_lds[16];
    int t = threadIdx.x;
    if (t < 208) {
        int c = t >> 4, sub = t & 15;
        float acc = 0.f;
        for (int k = sub * 64; k < sub * 64 + 64; ++k) {
            int p = k >> 5, q = k & 31;
            acc += x[(i * 32 + p) * W + (j * 32 + q)] * sw[(m * 13 + c) * 1024 + k];
        }
        #pragma unroll
        for (int off = 8; off; off >>= 1) acc += __shfl_down(acc, off, 16);
        if (sub == 0) s_lds[c] = acc;
    }
    __syncthreads();
    const float* uwm = uw + m * 1024 * 13;
    float* rm = r_all + m * NPIX;
    #pragma unroll
    for (int pi = 0; pi < 4; ++pi) {
        int px = pi * 256 + t;
        int p = px >> 5, q = px & 31;
        int oc = p * 32 + q;
        float acc = ub[m * 1024 + oc];
        #pragma unroll
        for (int c = 0; c < 13; ++c) acc = fmaf(uwm[oc * 13 + c], s_lds[c], acc);
        rm[((i * 32 + p) << 8) + j * 32 + q] = acc;
    }
}

// ---------------- h1 batched: conv 1->64 for all 8 m, writes padded planes
// m=0 -> f_all slot 0 ; m>=1 -> h_all slot m.
__global__ __launch_bounds__(256)
void h1_k(const float* __restrict__ r_all, const float* __restrict__ w,
          const float* __restrict__ b, const float* __restrict__ a,
          _Float16* __restrict__ f0, _Float16* __restrict__ hall)
{
    const int m = blockIdx.y;
    const float* r = r_all + m * NPIX;
    const float* wm = w + m * 576;
    const float* bm = b + m * 64;
    _Float16* outp = (m == 0) ? f0 : (hall + (size_t)m * PLANE);

    const int t = threadIdx.x;
    const int px = t & 63, cog = t >> 6;
    const int y = blockIdx.x >> 2;
    const int x = ((blockIdx.x & 3) << 6) + px;
    float v[9];
    #pragma unroll
    for (int dy = 0; dy < 3; ++dy) {
        int gy = y + dy - 1;
        #pragma unroll
        for (int dx = 0; dx < 3; ++dx) {
            int gx = x + dx - 1;
            v[dy*3+dx] = ((unsigned)gy < 256u && (unsigned)gx < 256u)
                       ? r[(gy << 8) + gx] : 0.f;
        }
    }
    const float slope = a[m];
    _Float16* op = outp + ((size_t)((y + 1) * PW + (x + 1))) * 64 + cog * 16;
    #pragma unroll
    for (int cg2 = 0; cg2 < 2; ++cg2) {
        half8 o;
        #pragma unroll
        for (int j = 0; j < 8; ++j) {
            int co = cog * 16 + cg2 * 8 + j;
            float acc = bm[co];
            #pragma unroll
            for (int k = 0; k < 9; ++k) acc = fmaf(v[k], wm[co*9+k], acc);
            acc = acc >= 0.f ? acc : slope * acc;
            o[j] = (_Float16)acc;
        }
        *(half8*)(op + cg2 * 8) = o;
    }
}

// ------- weight prep: fp32 [co][ci][9] -> f16 [blk][tap][kk][h][co][8]
// ci = (kk*2+h)*8+e. blocks 0-7: t2, 8-15: t3, 16-23: t4, 24+2f+half: fusion.
__global__ __launch_bounds__(256)
void wprep_k(const float* __restrict__ t2w, const float* __restrict__ t3w,
             const float* __restrict__ t4w, const float* __restrict__ fusw,
             _Float16* __restrict__ w16)
{
    int tid = blockIdx.x * 256 + threadIdx.x;
    if (tid >= 38 * 36864) return;
    int blk = tid / 36864, r2 = tid % 36864;
    int e = r2 & 7, co = (r2 >> 3) & 63, hh = (r2 >> 9) & 1, kk = (r2 >> 10) & 3,
        tap = r2 >> 12;
    const float* src; int cin, cib;
    if (blk < 24) {
        int which = blk >> 3, m = blk & 7;
        src = (which == 0 ? t2w : which == 1 ? t3w : t4w) + (size_t)m * 64 * 64 * 9;
        cin = 64; cib = 0;
    } else {
        int f = (blk - 24) >> 1; cib = ((blk - 24) & 1) * 64;
        src = fusw + (size_t)f * 64 * 128 * 9; cin = 128;
    }
    int ci = cib + (kk * 2 + hh) * 8 + e;
    w16[tid] = (_Float16)src[((size_t)co * cin + ci) * 9 + tap];
}

// ---------------- compute one 3-tap group (taps 3g..3g+2, weights in lw)
__device__ __forceinline__ void conv_taps3(
    const _Float16* __restrict__ li, const _Float16* __restrict__ lw,
    int g, int px0, int cl, int h,
    f32x16& acc00, f32x16& acc01, f32x16& acc10, f32x16& acc11)
{
    #pragma unroll
    for (int tt = 0; tt < 3; ++tt) {
        const int tap = g * 3 + tt;
        const int dy = tap / 3, dx = tap % 3;
        const int hx0 = px0 + cl + dx;
        const int hx1 = hx0 + 32;
        const int sw8 = hx0 & 7;               // (hx0+32)&7 == hx0&7
        #pragma unroll
        for (int kk = 0; kk < 4; ++kk) {
            const int c = kk * 2 + h;
            half8 a0 = *(const half8*)(lw + ((size_t)(((tt*4+kk)*2+h)*64 + cl)) * 8);
            half8 a1 = *(const half8*)(lw + ((size_t)(((tt*4+kk)*2+h)*64 + 32 + cl)) * 8);
            half8 b0 = *(const half8*)(li + ((size_t)((dy*130 + hx0)*8 + (c ^ sw8))) * 8);
            half8 b1 = *(const half8*)(li + ((size_t)((dy*130 + hx1)*8 + (c ^ sw8))) * 8);
            acc00 = __builtin_amdgcn_mfma_f32_32x32x16_f16(a0, b0, acc00, 0, 0, 0);
            acc01 = __builtin_amdgcn_mfma_f32_32x32x16_f16(a0, b1, acc01, 0, 0, 0);
            acc10 = __builtin_amdgcn_mfma_f32_32x32x16_f16(a1, b0, acc10, 0, 0, 0);
            acc11 = __builtin_amdgcn_mfma_f32_32x32x16_f16(a1, b1, acc11, 0, 0, 0);
        }
    }
}

// ---------------------------------------------- MFMA conv3x3 (64 ci / pass)
// grid (512, M): bid.x -> (y, x-half) XCD-banded; bid.y = m applies uniform
// strides (in/out += m*PLANE, w += m*36864, bias += m*64, alpha += m).
// PASSES=2 (fusion) is called with gridDim.y == 1.
template <int PASSES>
__global__ __launch_bounds__(128)
void conv_mfma_k(const _Float16* __restrict__ in0, const _Float16* __restrict__ in1,
                 const _Float16* __restrict__ w0, const _Float16* __restrict__ w1,
                 const float* __restrict__ bias, const float* __restrict__ alpha,
                 _Float16* __restrict__ out)
{
    const int m = blockIdx.y;
    in0  += (size_t)m * PLANE;
    out  += (size_t)m * PLANE;
    w0   += (size_t)m * 36864;
    bias += m * 64;
    alpha += m;

    const int t    = threadIdx.x;
    const int lane = t & 63;
    const int wv   = t >> 6;
    const int bid  = blockIdx.x;
    const int xcd  = bid & 7;
    const int idx  = bid >> 3;                      // [0,64)
    const int y    = xcd * 32 + (idx >> 1);         // XCD row-band mapping
    const int x0   = (idx & 1) << 7;                // 0 or 128
    const int h    = lane >> 5;
    const int cl   = lane & 31;
    const int px0  = wv * 64;

    extern __shared__ __align__(16) char smem[];
    _Float16* li = (_Float16*)smem;              // [3][130][8][8]  49920 B
    _Float16* lw = (_Float16*)(smem + 49920);    // [3][4][2][64][8] 24576 B

    f32x16 acc00, acc01, acc10, acc11;
    #pragma unroll
    for (int q = 0; q < 4; ++q)
        #pragma unroll
        for (int j = 0; j < 4; ++j) {
            int co = q * 8 + 4 * h + j;
            float b0 = bias[co], b1 = bias[co + 32];
            acc00[q*4+j] = b0; acc01[q*4+j] = b0;
            acc10[q*4+j] = b1; acc11[q*4+j] = b1;
        }

    #pragma unroll
    for (int pass = 0; pass < PASSES; ++pass) {
        const _Float16* in   = pass ? in1 : in0;
        const _Float16* wsrc = pass ? w1 : w0;
        if (pass) __syncthreads();               // LDS reuse fence
        // stage halo: 3*130*8 = 3120 chunks (pre-swizzled global source)
        #pragma unroll
        for (int i = 0; i < 25; ++i) {
            int f = i * 128 + t;
            if (i < 24 || f < 3120) {
                int r = f / 1040, rem = f % 1040;
                int hx = rem >> 3, c = rem & 7;
                const _Float16* src = in + ((size_t)((y + r) * PW + (x0 + hx)) * 64
                                            + (c ^ (hx & 7)) * 8);
                gl16(src, li + (size_t)f * 8);
            }
        }
        // stage weight group 0 (taps 0-2): 1536 chunks (linear)
        #pragma unroll
        for (int i = 0; i < 12; ++i) {
            int ch = i * 128 + t;
            gl16(wsrc + (size_t)ch * 8, lw + (size_t)ch * 8);
        }
        __syncthreads();                         // drains vmcnt
        conv_taps3(li, lw, 0, px0, cl, h, acc00, acc01, acc10, acc11);
        __syncthreads();
        #pragma unroll
        for (int i = 0; i < 12; ++i) {           // taps 3-5
            int ch = i * 128 + t;
            gl16(wsrc + (size_t)(1536 + ch) * 8, lw + (size_t)ch * 8);
        }
        __syncthreads();
        conv_taps3(li, lw, 1, px0, cl, h, acc00, acc01, acc10, acc11);
        __syncthreads();
        #pragma unroll
        for (int i = 0; i < 12; ++i) {           // taps 6-8
            int ch = i * 128 + t;
            gl16(wsrc + (size_t)(3072 + ch) * 8, lw + (size_t)ch * 8);
        }
        __syncthreads();
        conv_taps3(li, lw, 2, px0, cl, h, acc00, acc01, acc10, acc11);
    }

    // store: D col=lane&31=px, row=(r&3)+8*(r>>2)+4*h=co ; padded interior
    const float slope = alpha[0];
    #pragma unroll
    for (int pt = 0; pt < 2; ++pt) {
        const size_t gp = (size_t)((y + 1) * PW + (x0 + px0 + pt * 32 + cl + 1)) * 64;
        const f32x16& A0 = pt ? acc01 : acc00;
        const f32x16& A1 = pt ? acc11 : acc10;
        #pragma unroll
        for (int q = 0; q < 4; ++q) {
            half4 v0, v1;
            #pragma unroll
            for (int j = 0; j < 4; ++j) {
                float xv = A0[q*4+j]; xv = xv >= 0.f ? xv : slope * xv; v0[j] = (_Float16)xv;
                float yv = A1[q*4+j]; yv = yv >= 0.f ? yv : slope * yv; v1[j] = (_Float16)yv;
            }
            int co0 = q * 8 + 4 * h;
            *(half4*)(out + gp + co0)      = v0;
            *(half4*)(out + gp + co0 + 32) = v1;
        }
    }
}

// --------------------- t5 batched: conv 64->1 for all m (padded input)
__global__ __launch_bounds__(256)
void t5_k(const _Float16* __restrict__ in_all, const float* __restrict__ w_all,
          const float* __restrict__ b_all, float* __restrict__ out_all)
{
    const int m = blockIdx.y;
    const _Float16* in = in_all + (size_t)m * PLANE;
    const float* w = w_all + m * 576;
    float* out = out_all + m * NPIX;

    const int t = threadIdx.x;
    const int lane = t & 63, wv = t >> 6;
    const int px = t & 31, cg = t >> 5;
    const int y  = blockIdx.x >> 3;
    const int x0 = (blockIdx.x & 7) << 5;
    const int x  = x0 + px;

    __shared__ float wl[576];
    __shared__ float part[4][32];
    #pragma unroll
    for (int i = 0; i < 3; ++i) {
        int idxw = i * 256 + t;
        if (idxw < 576) wl[idxw] = w[idxw];
    }
    __syncthreads();

    float acc = 0.f;
    #pragma unroll
    for (int dy = 0; dy < 3; ++dy)
        #pragma unroll
        for (int dx = 0; dx < 3; ++dx) {
            half8 vv = *(const half8*)(in + (size_t)((y + dy) * PW + (x + dx)) * 64 + cg * 8);
            int tap = dy * 3 + dx;
            #pragma unroll
            for (int e = 0; e < 8; ++e)
                acc = fmaf((float)vv[e], wl[(cg * 8 + e) * 9 + tap], acc);
        }
    acc += __shfl_xor(acc, 32, 64);
    if (lane < 32) part[wv][lane] = acc;
    __syncthreads();
    if (t < 32) {
        float s = part[0][t] + part[1][t] + part[2][t] + part[3][t] + b_all[m];
        out[(y << 8) + x0 + t] = s;
    }
}

extern "C" void kernel_launch(void* const* d_in, const int* in_sizes, int n_in,
                              void* d_out, int out_size, void* d_ws, size_t ws_size,
                              hipStream_t stream)
{
    const float* x        = (const float*)d_in[0];
    const float* sample_w = (const float*)d_in[1];
    const float* up_w     = (const float*)d_in[2];
    const float* up_b     = (const float*)d_in[3];
    const float* h1_w     = (const float*)d_in[4];
    const float* h1_b     = (const float*)d_in[5];
    const float* h1_a     = (const float*)d_in[6];
    const float* fus_w    = (const float*)d_in[7];
    const float* fus_b    = (const float*)d_in[8];
    const float* fus_a    = (const float*)d_in[9];
    const float* t2_w     = (const float*)d_in[10];
    const float* t2_b     = (const float*)d_in[11];
    const float* t2_a     = (const float*)d_in[12];
    const float* t3_w     = (const float*)d_in[13];
    const float* t3_b     = (const float*)d_in[14];
    const float* t3_a     = (const float*)d_in[15];
    const float* t4_w     = (const float*)d_in[16];
    const float* t4_b     = (const float*)d_in[17];
    const float* t4_a     = (const float*)d_in[18];
    const float* t5_w     = (const float*)d_in[19];
    const float* t5_b     = (const float*)d_in[20];

    float* out = (float*)d_out;
    char*  wsb = (char*)d_ws;

    _Float16* w16    = (_Float16*)wsb;                  //   2,801,664 B
    float*    r_all  = (float*)(wsb + 2801664);         //   2,097,152 B
    _Float16* f_all  = (_Float16*)(wsb + 4898816);      // 8 planes
    _Float16* h_all  = f_all + 8 * PLANE;               // 8 planes
    _Float16* t1_all = h_all + 8 * PLANE;               // 8 planes  (~209 MB total)

    auto wblk = [&](int b) { return w16 + (size_t)b * 36864; };

    border_k<<<771, 256, 0, stream>>>(f_all);           // zero 24 plane borders
    wprep_k<<<5472, 256, 0, stream>>>(t2_w, t3_w, t4_w, fus_w, w16);
    sampup_k<<<512, 256, 0, stream>>>(x, sample_w, up_w, up_b, r_all);
    h1_k<<<dim3(1024, 8), 256, 0, stream>>>(r_all, h1_w, h1_b, h1_a, f_all, h_all);

    const size_t LDSB = 49920 + 24576;                  // 74496 B -> 2 blk/CU
    for (int m = 1; m < 8; ++m) {
        conv_mfma_k<2><<<dim3(512, 1), 128, LDSB, stream>>>(
            f_all + (size_t)(m - 1) * PLANE, h_all + (size_t)m * PLANE,
            wblk(24 + (m - 1) * 2), wblk(24 + (m - 1) * 2 + 1),
            fus_b + (m - 1) * 64, fus_a + (m - 1), f_all + (size_t)m * PLANE);
    }
    conv_mfma_k<1><<<dim3(512, 8), 128, LDSB, stream>>>(
        f_all, nullptr, wblk(0), nullptr, t2_b, t2_a, t1_all);
    conv_mfma_k<1><<<dim3(512, 8), 128, LDSB, stream>>>(
        t1_all, nullptr, wblk(8), nullptr, t3_b, t3_a, h_all);
    conv_mfma_k<1><<<dim3(512, 8), 128, LDSB, stream>>>(
        h_all, nullptr, wblk(16), nullptr, t4_b, t4_a, t1_all);
    t5_k<<<dim3(2048, 8), 256, 0, stream>>>(t1_all, t5_w, t5_b, out);
}

// Round 7
// 456.664 us; speedup vs baseline: 29.6823x; 1.0071x over previous
//
#include <hip/hip_runtime.h>

// HierarchicalCSNet — f16 MFMA implicit-GEMM, 4-wave co-split blocks.
// Feature planes: padded NHWC f16 [258][258][64], borders zero (= conv pad).
// conv3x3: block = 4 waves (256 thr), tile 64co x 128px (half row).
//   Wave = 32co x 64px: per (tap,kk) 1 A-read + 2 B-reads -> 2 MFMA.
//   LDS: halo [3][130][8][8] = 49920 B + weight buf (3 taps) 24576 B = 74.5 KB
//   -> 2 blocks/CU (8 waves/CU, 2/SIMD): phases of the two blocks overlap.
// Schedule: border/wprep/sampup -> h1-all -> 7x fusion (serial) ->
//   t2-all -> t3-all -> t4-all -> t5-all.
constexpr int H = 256, W = 256, NPIX = H * W;
constexpr int PW = 258;
constexpr size_t PLANE = (size_t)PW * PW * 64;      // f16 elements per plane

typedef _Float16 half8 __attribute__((ext_vector_type(8)));
typedef _Float16 half4 __attribute__((ext_vector_type(4)));
typedef float    f32x4 __attribute__((ext_vector_type(4)));
typedef float    f32x16 __attribute__((ext_vector_type(16)));

__device__ __forceinline__ void gl16(const _Float16* g, _Float16* l)
{
    __builtin_amdgcn_global_load_lds(
        (const __attribute__((address_space(1))) unsigned int*)g,
        (__attribute__((address_space(3))) unsigned int*)l, 16, 0, 0);
}

// --------------------------------------------------- border zero (24 planes)
__global__ __launch_bounds__(256)
void border_k(_Float16* __restrict__ planes)
{
    int tid = blockIdx.x * 256 + threadIdx.x;
    if (tid >= 24 * 1028 * 8) return;
    int c = tid & 7, rem = tid >> 3;
    int p = rem / 1028, b = rem % 1028;
    int gy, gx;
    if (b < 258)      { gy = 0;           gx = b; }
    else if (b < 516) { gy = 257;         gx = b - 258; }
    else if (b < 772) { gy = b - 516 + 1; gx = 0; }
    else              { gy = b - 772 + 1; gx = 257; }
    f32x4 z = {0.f, 0.f, 0.f, 0.f};
    *(f32x4*)(planes + (size_t)p * PLANE + ((size_t)(gy * PW + gx) * 64) + c * 8) = z;
}

// --------------------------- fused sampling + up(1x1) + reshape_adap (all m)
__global__ __launch_bounds__(256)
void sampup_k(const float* __restrict__ x, const float* __restrict__ sw,
              const float* __restrict__ uw, const float* __restrict__ ub,
              float* __restrict__ r_all)
{
    int m = blockIdx.x >> 6, ij = blockIdx.x & 63;
    int i = ij >> 3, j = ij & 7;
    __shared__ float s_lds[16];
    int t = threadIdx.x;
    if (t < 208) {
        int c = t >> 4, sub = t & 15;
        float acc = 0.f;
        for (int k = sub * 64; k < sub * 64 + 64; ++k) {
            int p = k >> 5, q = k & 31;
            acc += x[(i * 32 + p) * W + (j * 32 + q)] * sw[(m * 13 + c) * 1024 + k];
        }
        #pragma unroll
        for (int off = 8; off; off >>= 1) acc += __shfl_down(acc, off, 16);
        if (sub == 0) s_lds[c] = acc;
    }
    __syncthreads();
    const float* uwm = uw + m * 1024 * 13;
    float* rm = r_all + m * NPIX;
    #pragma unroll
    for (int pi = 0; pi < 4; ++pi) {
        int px = pi * 256 + t;
        int p = px >> 5, q = px & 31;
        int oc = p * 32 + q;
        float acc = ub[m * 1024 + oc];
        #pragma unroll
        for (int c = 0; c < 13; ++c) acc = fmaf(uwm[oc * 13 + c], s_lds[c], acc);
        rm[((i * 32 + p) << 8) + j * 32 + q] = acc;
    }
}

// ---------------- h1 batched: conv 1->64 for all 8 m, writes padded planes
__global__ __launch_bounds__(256)
void h1_k(const float* __restrict__ r_all, const float* __restrict__ w,
          const float* __restrict__ b, const float* __restrict__ a,
          _Float16* __restrict__ f0, _Float16* __restrict__ hall)
{
    const int m = blockIdx.y;
    const float* r = r_all + m * NPIX;
    const float* wm = w + m * 576;
    const float* bm = b + m * 64;
    _Float16* outp = (m == 0) ? f0 : (hall + (size_t)m * PLANE);

    const int t = threadIdx.x;
    const int px = t & 63, cog = t >> 6;
    const int y = blockIdx.x >> 2;
    const int x = ((blockIdx.x & 3) << 6) + px;
    float v[9];
    #pragma unroll
    for (int dy = 0; dy < 3; ++dy) {
        int gy = y + dy - 1;
        #pragma unroll
        for (int dx = 0; dx < 3; ++dx) {
            int gx = x + dx - 1;
            v[dy*3+dx] = ((unsigned)gy < 256u && (unsigned)gx < 256u)
                       ? r[(gy << 8) + gx] : 0.f;
        }
    }
    const float slope = a[m];
    _Float16* op = outp + ((size_t)((y + 1) * PW + (x + 1))) * 64 + cog * 16;
    #pragma unroll
    for (int cg2 = 0; cg2 < 2; ++cg2) {
        half8 o;
        #pragma unroll
        for (int j = 0; j < 8; ++j) {
            int co = cog * 16 + cg2 * 8 + j;
            float acc = bm[co];
            #pragma unroll
            for (int k = 0; k < 9; ++k) acc = fmaf(v[k], wm[co*9+k], acc);
            acc = acc >= 0.f ? acc : slope * acc;
            o[j] = (_Float16)acc;
        }
        *(half8*)(op + cg2 * 8) = o;
    }
}

// ------- weight prep: fp32 [co][ci][9] -> f16 [blk][tap][kk][h][co][8]
// ci = (kk*2+h)*8+e. blocks 0-7: t2, 8-15: t3, 16-23: t4, 24+2f+half: fusion.
__global__ __launch_bounds__(256)
void wprep_k(const float* __restrict__ t2w, const float* __restrict__ t3w,
             const float* __restrict__ t4w, const float* __restrict__ fusw,
             _Float16* __restrict__ w16)
{
    int tid = blockIdx.x * 256 + threadIdx.x;
    if (tid >= 38 * 36864) return;
    int blk = tid / 36864, r2 = tid % 36864;
    int e = r2 & 7, co = (r2 >> 3) & 63, hh = (r2 >> 9) & 1, kk = (r2 >> 10) & 3,
        tap = r2 >> 12;
    const float* src; int cin, cib;
    if (blk < 24) {
        int which = blk >> 3, m = blk & 7;
        src = (which == 0 ? t2w : which == 1 ? t3w : t4w) + (size_t)m * 64 * 64 * 9;
        cin = 64; cib = 0;
    } else {
        int f = (blk - 24) >> 1; cib = ((blk - 24) & 1) * 64;
        src = fusw + (size_t)f * 64 * 128 * 9; cin = 128;
    }
    int ci = cib + (kk * 2 + hh) * 8 + e;
    w16[tid] = (_Float16)src[((size_t)co * cin + ci) * 9 + tap];
}

// ---------------- compute one 3-tap group (taps 3g..3g+2, weights in lw)
// Wave = 32co (cohalf) x 64px (2 subtiles). 1 A-read + 2 B-reads -> 2 MFMA.
__device__ __forceinline__ void conv_taps3(
    const _Float16* __restrict__ li, const _Float16* __restrict__ lw,
    int px0, int cl, int h, int cobase,
    f32x16& acc0, f32x16& acc1)
{
    __builtin_amdgcn_s_setprio(1);
    #pragma unroll
    for (int tt = 0; tt < 3; ++tt) {
        const int dy = __builtin_amdgcn_readfirstlane(0);  // placeholder no-op
        (void)dy;
    }
    __builtin_amdgcn_s_setprio(0);
}

// ---------------------------------------------- MFMA conv3x3 (64 ci / pass)
// grid (512, M): bid.x -> (y, x-half) XCD-banded; bid.y = m uniform strides.
template <int PASSES>
__global__ __launch_bounds__(256, 2)
void conv_mfma_k(const _Float16* __restrict__ in0, const _Float16* __restrict__ in1,
                 const _Float16* __restrict__ w0, const _Float16* __restrict__ w1,
                 const float* __restrict__ bias, const float* __restrict__ alpha,
                 _Float16* __restrict__ out)
{
    const int m = blockIdx.y;
    in0  += (size_t)m * PLANE;
    out  += (size_t)m * PLANE;
    w0   += (size_t)m * 36864;
    bias += m * 64;
    alpha += m;

    const int t    = threadIdx.x;
    const int lane = t & 63;
    const int wv   = t >> 6;                        // 4 waves
    const int bid  = blockIdx.x;
    const int xcd  = bid & 7;
    const int idx  = bid >> 3;                      // [0,64)
    const int y    = xcd * 32 + (idx >> 1);         // XCD row-band mapping
    const int x0   = (idx & 1) << 7;                // 0 or 128
    const int h    = lane >> 5;
    const int cl   = lane & 31;
    const int cohalf = wv >> 1;                     // 0/1: co 32-block
    const int px0    = (wv & 1) * 64;               // 0/64 within the 128 tile
    const int cobase = cohalf * 32;

    extern __shared__ __align__(16) char smem[];
    _Float16* li = (_Float16*)smem;              // [3][130][8][8]  49920 B
    _Float16* lw = (_Float16*)(smem + 49920);    // [3][4][2][64][8] 24576 B

    f32x16 acc0, acc1;                           // px-subtiles 0 / 1
    #pragma unroll
    for (int q = 0; q < 4; ++q)
        #pragma unroll
        for (int j = 0; j < 4; ++j) {
            float b0 = bias[cobase + q * 8 + 4 * h + j];
            acc0[q*4+j] = b0; acc1[q*4+j] = b0;
        }

    #pragma unroll
    for (int pass = 0; pass < PASSES; ++pass) {
        const _Float16* in   = pass ? in1 : in0;
        const _Float16* wsrc = pass ? w1 : w0;
        if (pass) __syncthreads();               // LDS reuse fence
        // stage halo: 3*130*8 = 3120 chunks (pre-swizzled global source)
        #pragma unroll
        for (int i = 0; i < 13; ++i) {
            int f = i * 256 + t;
            if (i < 12 || f < 3120) {
                int r = f / 1040, rem = f % 1040;
                int hx = rem >> 3, c = rem & 7;
                const _Float16* src = in + ((size_t)((y + r) * PW + (x0 + hx)) * 64
                                            + (c ^ (hx & 7)) * 8);
                gl16(src, li + (size_t)f * 8);
            }
        }
        // stage weight group 0 (taps 0-2): 1536 chunks (linear)
        #pragma unroll
        for (int i = 0; i < 6; ++i) {
            int ch = i * 256 + t;
            gl16(wsrc + (size_t)ch * 8, lw + (size_t)ch * 8);
        }
        __syncthreads();                         // drains vmcnt

        #pragma unroll
        for (int g = 0; g < 3; ++g) {
            if (g) {                             // stage group g (taps 3g..)
                __syncthreads();
                #pragma unroll
                for (int i = 0; i < 6; ++i) {
                    int ch = i * 256 + t;
                    gl16(wsrc + (size_t)(g * 1536 + ch) * 8, lw + (size_t)ch * 8);
                }
                __syncthreads();
            }
            __builtin_amdgcn_s_setprio(1);
            #pragma unroll
            for (int tt = 0; tt < 3; ++tt) {
                const int tap = g * 3 + tt;
                const int dy = tap / 3, dx = tap % 3;
                const int hx0 = px0 + cl + dx;
                const int hx1 = hx0 + 32;
                const int sw8 = hx0 & 7;         // (hx0+32)&7 == hx0&7
                #pragma unroll
                for (int kk = 0; kk < 4; ++kk) {
                    const int c = kk * 2 + h;
                    half8 a  = *(const half8*)(lw + ((size_t)(((tt*4+kk)*2+h)*64 + cobase + cl)) * 8);
                    half8 b0 = *(const half8*)(li + ((size_t)((dy*130 + hx0)*8 + (c ^ sw8))) * 8);
                    half8 b1 = *(const half8*)(li + ((size_t)((dy*130 + hx1)*8 + (c ^ sw8))) * 8);
                    acc0 = __builtin_amdgcn_mfma_f32_32x32x16_f16(a, b0, acc0, 0, 0, 0);
                    acc1 = __builtin_amdgcn_mfma_f32_32x32x16_f16(a, b1, acc1, 0, 0, 0);
                }
            }
            __builtin_amdgcn_s_setprio(0);
        }
    }

    // store: D col=lane&31=px, row=(r&3)+8*(r>>2)+4*h (+cobase) ; padded interior
    const float slope = alpha[0];
    #pragma unroll
    for (int pt = 0; pt < 2; ++pt) {
        const size_t gp = (size_t)((y + 1) * PW + (x0 + px0 + pt * 32 + cl + 1)) * 64;
        const f32x16& A0 = pt ? acc1 : acc0;
        #pragma unroll
        for (int q = 0; q < 4; ++q) {
            half4 v0;
            #pragma unroll
            for (int j = 0; j < 4; ++j) {
                float xv = A0[q*4+j]; xv = xv >= 0.f ? xv : slope * xv; v0[j] = (_Float16)xv;
            }
            *(half4*)(out + gp + cobase + q * 8 + 4 * h) = v0;
        }
    }
}

// --------------------- t5 batched: conv 64->1 for all m (padded input)
__global__ __launch_bounds__(256)
void t5_k(const _Float16* __restrict__ in_all, const float* __restrict__ w_all,
          const float* __restrict__ b_all, float* __restrict__ out_all)
{
    const int m = blockIdx.y;
    const _Float16* in = in_all + (size_t)m * PLANE;
    const float* w = w_all + m * 576;
    float* out = out_all + m * NPIX;

    const int t = threadIdx.x;
    const int lane = t & 63, wv = t >> 6;
    const int px = t & 31, cg = t >> 5;
    const int y  = blockIdx.x >> 3;
    const int x0 = (blockIdx.x & 7) << 5;
    const int x  = x0 + px;

    __shared__ float wl[576];
    __shared__ float part[4][32];
    #pragma unroll
    for (int i = 0; i < 3; ++i) {
        int idxw = i * 256 + t;
        if (idxw < 576) wl[idxw] = w[idxw];
    }
    __syncthreads();

    float acc = 0.f;
    #pragma unroll
    for (int dy = 0; dy < 3; ++dy)
        #pragma unroll
        for (int dx = 0; dx < 3; ++dx) {
            half8 vv = *(const half8*)(in + (size_t)((y + dy) * PW + (x + dx)) * 64 + cg * 8);
            int tap = dy * 3 + dx;
            #pragma unroll
            for (int e = 0; e < 8; ++e)
                acc = fmaf((float)vv[e], wl[(cg * 8 + e) * 9 + tap], acc);
        }
    acc += __shfl_xor(acc, 32, 64);
    if (lane < 32) part[wv][lane] = acc;
    __syncthreads();
    if (t < 32) {
        float s = part[0][t] + part[1][t] + part[2][t] + part[3][t] + b_all[m];
        out[(y << 8) + x0 + t] = s;
    }
}

extern "C" void kernel_launch(void* const* d_in, const int* in_sizes, int n_in,
                              void* d_out, int out_size, void* d_ws, size_t ws_size,
                              hipStream_t stream)
{
    const float* x        = (const float*)d_in[0];
    const float* sample_w = (const float*)d_in[1];
    const float* up_w     = (const float*)d_in[2];
    const float* up_b     = (const float*)d_in[3];
    const float* h1_w     = (const float*)d_in[4];
    const float* h1_b     = (const float*)d_in[5];
    const float* h1_a     = (const float*)d_in[6];
    const float* fus_w    = (const float*)d_in[7];
    const float* fus_b    = (const float*)d_in[8];
    const float* fus_a    = (const float*)d_in[9];
    const float* t2_w     = (const float*)d_in[10];
    const float* t2_b     = (const float*)d_in[11];
    const float* t2_a     = (const float*)d_in[12];
    const float* t3_w     = (const float*)d_in[13];
    const float* t3_b     = (const float*)d_in[14];
    const float* t3_a     = (const float*)d_in[15];
    const float* t4_w     = (const float*)d_in[16];
    const float* t4_b     = (const float*)d_in[17];
    const float* t4_a     = (const float*)d_in[18];
    const float* t5_w     = (const float*)d_in[19];
    const float* t5_b     = (const float*)d_in[20];

    float* out = (float*)d_out;
    char*  wsb = (char*)d_ws;

    _Float16* w16    = (_Float16*)wsb;                  //   2,801,664 B
    float*    r_all  = (float*)(wsb + 2801664);         //   2,097,152 B
    _Float16* f_all  = (_Float16*)(wsb + 4898816);      // 8 planes
    _Float16* h_all  = f_all + 8 * PLANE;               // 8 planes
    _Float16* t1_all = h_all + 8 * PLANE;               // 8 planes

    auto wblk = [&](int b) { return w16 + (size_t)b * 36864; };

    border_k<<<771, 256, 0, stream>>>(f_all);           // zero 24 plane borders
    wprep_k<<<5472, 256, 0, stream>>>(t2_w, t3_w, t4_w, fus_w, w16);
    sampup_k<<<512, 256, 0, stream>>>(x, sample_w, up_w, up_b, r_all);
    h1_k<<<dim3(1024, 8), 256, 0, stream>>>(r_all, h1_w, h1_b, h1_a, f_all, h_all);

    const size_t LDSB = 49920 + 24576;                  // 74496 B -> 2 blk/CU
    for (int m = 1; m < 8; ++m) {
        conv_mfma_k<2><<<dim3(512, 1), 256, LDSB, stream>>>(
            f_all + (size_t)(m - 1) * PLANE, h_all + (size_t)m * PLANE,
            wblk(24 + (m - 1) * 2), wblk(24 + (m - 1) * 2 + 1),
            fus_b + (m - 1) * 64, fus_a + (m - 1), f_all + (size_t)m * PLANE);
    }
    conv_mfma_k<1><<<dim3(512, 8), 256, LDSB, stream>>>(
        f_all, nullptr, wblk(0), nullptr, t2_b, t2_a, t1_all);
    conv_mfma_k<1><<<dim3(512, 8), 256, LDSB, stream>>>(
        t1_all, nullptr, wblk(8), nullptr, t3_b, t3_a, h_all);
    conv_mfma_k<1><<<dim3(512, 8), 256, LDSB, stream>>>(
        h_all, nullptr, wblk(16), nullptr, t4_b, t4_a, t1_all);
    t5_k<<<dim3(2048, 8), 256, 0, stream>>>(t1_all, t5_w, t5_b, out);
}